// Round 15
// baseline (118.629 us; speedup 1.0000x reference)
//
#include <hip/hip_runtime.h>
#include <hip/hip_bf16.h>
#include <cmath>

typedef __bf16 bf16_t;
typedef __bf16 bf16x8 __attribute__((ext_vector_type(8)));
typedef __bf16 bf16x4 __attribute__((ext_vector_type(4)));
typedef float f32x4 __attribute__((ext_vector_type(4)));

#define QLEN 2048
#define DMODEL 512
#define NH 8
#define DKV 64
#define INNER 512
#define LOG2E 1.44269504f
#define THR_LOG2 11.5415603f   // 8 * log2(e)

// ---------- prep: 4 weight transposes fused: Wt[n][k] = W[k][n], hi/lo split ----------
__global__ __launch_bounds__(256) void transpose512_split_all(
    const float* __restrict__ W0, const float* __restrict__ W1,
    const float* __restrict__ W2, const float* __restrict__ W3,
    bf16_t* __restrict__ H0, bf16_t* __restrict__ L0,
    bf16_t* __restrict__ H1, bf16_t* __restrict__ L1,
    bf16_t* __restrict__ H2, bf16_t* __restrict__ L2,
    bf16_t* __restrict__ H3, bf16_t* __restrict__ L3) {
  __shared__ float tile[32][33];
  int z = blockIdx.z;
  const float* W = z == 0 ? W0 : z == 1 ? W1 : z == 2 ? W2 : W3;
  bf16_t* Whi    = z == 0 ? H0 : z == 1 ? H1 : z == 2 ? H2 : H3;
  bf16_t* Wlo    = z == 0 ? L0 : z == 1 ? L1 : z == 2 ? L2 : L3;
  int bk = blockIdx.x * 32, bn = blockIdx.y * 32;
  int tx = threadIdx.x, ty = threadIdx.y;
  #pragma unroll
  for (int i = 0; i < 32; i += 8)
    tile[ty + i][tx] = W[(size_t)(bk + ty + i) * DMODEL + bn + tx];
  __syncthreads();
  #pragma unroll
  for (int i = 0; i < 32; i += 8) {
    float v = tile[tx][ty + i];
    bf16_t hb = (bf16_t)v;
    size_t o = (size_t)(bn + ty + i) * DMODEL + bk + tx;
    Whi[o] = hb;
    Wlo[o] = (bf16_t)(v - (float)hb);
  }
}

// ---------- helpers ----------
__device__ __forceinline__ void splitx8(const float4& v0, const float4& v1,
                                        bf16x8& h, bf16x8& l) {
  #pragma unroll
  for (int j = 0; j < 4; ++j) {
    float x = (&v0.x)[j];
    bf16_t hb = (bf16_t)x;
    h[j] = hb; l[j] = (bf16_t)(x - (float)hb);
  }
  #pragma unroll
  for (int j = 0; j < 4; ++j) {
    float x = (&v1.x)[j];
    bf16_t hb = (bf16_t)x;
    h[4 + j] = hb; l[4 + j] = (bf16_t)(x - (float)hb);
  }
}

#define GST 72

// ---------- fused Q+K+V projection: grid (64, 12) ----------
// y>>2: 0=Q (3-pass, *log2e, hi/lo out), 1=K (3-pass, hi out), 2=V (1-pass, V^T out).
// A = X f32, split hi/lo during staging.
__global__ __launch_bounds__(256) void gemm_qkv(const float* __restrict__ X,
                                                const bf16_t* __restrict__ Wqh,
                                                const bf16_t* __restrict__ Wql,
                                                const bf16_t* __restrict__ Wkh,
                                                const bf16_t* __restrict__ Wkl,
                                                const bf16_t* __restrict__ Wvh,
                                                bf16_t* __restrict__ Qh,
                                                bf16_t* __restrict__ Ql,
                                                bf16_t* __restrict__ Kh,
                                                bf16_t* __restrict__ Vt) {
  __shared__ bf16_t sAh[64 * GST];
  __shared__ bf16_t sAl[64 * GST];
  __shared__ bf16_t sBh[128 * GST];
  __shared__ bf16_t sBl[128 * GST];
  const int m0 = blockIdx.x * 64;
  const int y = blockIdx.y;
  const int kind = y >> 2;           // 0=Q 1=K 2=V
  const int n0 = (y & 3) * 128;
  const bf16_t* __restrict__ Bh = kind == 0 ? Wqh : kind == 1 ? Wkh : Wvh;
  const bf16_t* __restrict__ Bl = kind == 0 ? Wql : Wkl;   // unused when kind==2

  const int tid = threadIdx.x;
  const int lane = tid & 63, w = tid >> 6;
  const int wr = (w >> 1) * 32, wc = (w & 1) * 64;
  const int l16 = lane & 15, lg = lane >> 4;

  f32x4 acc[2][4] = {};

  for (int k0 = 0; k0 < DMODEL; k0 += 64) {
    #pragma unroll
    for (int i = 0; i < 2; ++i) {
      int chunk = tid + i * 256;
      int row = chunk >> 3, c8 = (chunk & 7) * 8;
      const float4* src = reinterpret_cast<const float4*>(
          &X[(size_t)(m0 + row) * DMODEL + k0 + c8]);
      bf16x8 h, l;
      splitx8(src[0], src[1], h, l);
      *reinterpret_cast<bf16x8*>(&sAh[row * GST + c8]) = h;
      *reinterpret_cast<bf16x8*>(&sAl[row * GST + c8]) = l;
    }
    #pragma unroll
    for (int i = 0; i < 4; ++i) {
      int chunk = tid + i * 256;
      int row = chunk >> 3, c8 = (chunk & 7) * 8;
      size_t gb = (size_t)(n0 + row) * DMODEL + k0 + c8;
      *reinterpret_cast<bf16x8*>(&sBh[row * GST + c8]) = *reinterpret_cast<const bf16x8*>(&Bh[gb]);
      if (kind < 2)
        *reinterpret_cast<bf16x8*>(&sBl[row * GST + c8]) = *reinterpret_cast<const bf16x8*>(&Bl[gb]);
    }
    __syncthreads();
    #pragma unroll
    for (int ks = 0; ks < 2; ++ks) {
      bf16x8 ah[2], al[2], bh[4], bl[4];
      #pragma unroll
      for (int i = 0; i < 2; ++i) {
        int ro = (wr + i * 16 + l16) * GST + ks * 32 + lg * 8;
        ah[i] = *reinterpret_cast<const bf16x8*>(&sAh[ro]);
        al[i] = *reinterpret_cast<const bf16x8*>(&sAl[ro]);
      }
      #pragma unroll
      for (int j = 0; j < 4; ++j) {
        int ro = (wc + j * 16 + l16) * GST + ks * 32 + lg * 8;
        bh[j] = *reinterpret_cast<const bf16x8*>(&sBh[ro]);
        bl[j] = *reinterpret_cast<const bf16x8*>(&sBl[ro]);
      }
      #pragma unroll
      for (int i = 0; i < 2; ++i)
        #pragma unroll
        for (int j = 0; j < 4; ++j)
          acc[i][j] = __builtin_amdgcn_mfma_f32_16x16x32_bf16(ah[i], bh[j], acc[i][j], 0, 0, 0);
      if (kind < 2) {
        #pragma unroll
        for (int i = 0; i < 2; ++i)
          #pragma unroll
          for (int j = 0; j < 4; ++j) {
            acc[i][j] = __builtin_amdgcn_mfma_f32_16x16x32_bf16(ah[i], bl[j], acc[i][j], 0, 0, 0);
            acc[i][j] = __builtin_amdgcn_mfma_f32_16x16x32_bf16(al[i], bh[j], acc[i][j], 0, 0, 0);
          }
      }
    }
    __syncthreads();
  }

  #pragma unroll
  for (int i = 0; i < 2; ++i)
    #pragma unroll
    for (int j = 0; j < 4; ++j)
      #pragma unroll
      for (int r = 0; r < 4; ++r) {
        int m = m0 + wr + i * 16 + lg * 4 + r;
        int n = n0 + wc + j * 16 + l16;
        float v = acc[i][j][r];
        if (kind == 0) {
          v *= LOG2E;
          bf16_t hb = (bf16_t)v;
          size_t o = (size_t)m * INNER + n;
          Qh[o] = hb;
          Ql[o] = (bf16_t)(v - (float)hb);
        } else if (kind == 1) {
          Kh[(size_t)m * INNER + n] = (bf16_t)v;
        } else {
          int b = m >> 11, s = m & (QLEN - 1);
          Vt[(size_t)(b * INNER + n) * QLEN + s] = (bf16_t)v;
        }
      }
}

// ---------- output projection GEMM: BM=BN=64, f32 out ----------
__global__ __launch_bounds__(256) void gemm_out(const bf16_t* __restrict__ A,
                                                const bf16_t* __restrict__ Bt,
                                                float* __restrict__ Cf) {
  __shared__ bf16_t sA[64 * GST];
  __shared__ bf16_t sB[64 * GST];
  const int m0 = blockIdx.x * 64, n0 = blockIdx.y * 64;
  const int tid = threadIdx.x;
  const int lane = tid & 63, w = tid >> 6;
  const int wr = (w >> 1) * 32, wc = (w & 1) * 32;
  const int l16 = lane & 15, lg = lane >> 4;

  f32x4 acc[2][2] = {};

  for (int k0 = 0; k0 < DMODEL; k0 += 64) {
    #pragma unroll
    for (int i = 0; i < 2; ++i) {
      int chunk = tid + i * 256;
      int row = chunk >> 3, c8 = (chunk & 7) * 8;
      *reinterpret_cast<bf16x8*>(&sA[row * GST + c8]) =
          *reinterpret_cast<const bf16x8*>(&A[(size_t)(m0 + row) * DMODEL + k0 + c8]);
      *reinterpret_cast<bf16x8*>(&sB[row * GST + c8]) =
          *reinterpret_cast<const bf16x8*>(&Bt[(size_t)(n0 + row) * DMODEL + k0 + c8]);
    }
    __syncthreads();
    #pragma unroll
    for (int ks = 0; ks < 2; ++ks) {
      bf16x8 af[2], bfr[2];
      #pragma unroll
      for (int i = 0; i < 2; ++i)
        af[i] = *reinterpret_cast<const bf16x8*>(&sA[(wr + i * 16 + l16) * GST + ks * 32 + lg * 8]);
      #pragma unroll
      for (int j = 0; j < 2; ++j)
        bfr[j] = *reinterpret_cast<const bf16x8*>(&sB[(wc + j * 16 + l16) * GST + ks * 32 + lg * 8]);
      #pragma unroll
      for (int i = 0; i < 2; ++i)
        #pragma unroll
        for (int j = 0; j < 2; ++j)
          acc[i][j] = __builtin_amdgcn_mfma_f32_16x16x32_bf16(af[i], bfr[j], acc[i][j], 0, 0, 0);
    }
    __syncthreads();
  }

  #pragma unroll
  for (int i = 0; i < 2; ++i)
    #pragma unroll
    for (int j = 0; j < 2; ++j)
      #pragma unroll
      for (int r = 0; r < 4; ++r) {
        int m = m0 + wr + i * 16 + lg * 4 + r;
        int n = n0 + wc + j * 16 + l16;
        Cf[(size_t)m * DMODEL + n] = acc[i][j][r];
      }
}

// ---------- attention helpers ----------
__device__ __forceinline__ float redmax16(float v) {
  v = fmaxf(v, __shfl_xor(v, 1));
  v = fmaxf(v, __shfl_xor(v, 2));
  v = fmaxf(v, __shfl_xor(v, 4));
  v = fmaxf(v, __shfl_xor(v, 8));
  return v;
}
__device__ __forceinline__ float redsum16(float v) {
  v += __shfl_xor(v, 1);
  v += __shfl_xor(v, 2);
  v += __shfl_xor(v, 4);
  v += __shfl_xor(v, 8);
  return v;
}
__device__ __forceinline__ int t5_bucket_abs(int n) {
  if (n < 8)  return n;
  if (n < 12) return 8;
  if (n < 16) return 9;
  if (n < 23) return 10;
  if (n < 32) return 11;
  if (n < 46) return 12;
  if (n < 64) return 13;
  if (n < 91) return 14;
  return 15;
}

// ---------- flash attention (R9/R14 structure, hoisted staging addresses) ----------
#define SPS 68    // sP row stride (bf16) and sAcc row stride (f32)
#define SVS 136   // sV row stride (bf16)

__global__ __launch_bounds__(512, 4) void attn_kernel(const bf16_t* __restrict__ Qh,
                                                      const bf16_t* __restrict__ Ql,
                                                      const bf16_t* __restrict__ Kh,
                                                      const bf16_t* __restrict__ Vt,
                                                      const float* __restrict__ relb,
                                                      bf16_t* __restrict__ ctx) {
  __shared__ bf16_t sKh[128 * 72];        // 18432 B
  __shared__ bf16_t sV [64 * SVS];        // 17408 B
  __shared__ bf16_t sP [2][64 * SPS];     // 17408 B (aliased as f32 sAcc in merge)
  __shared__ float sM[2][64], sL[2][64];  // 1024 B
  __shared__ float sBiasH[32];
  float* sAcc = (float*)&sP[0][0];

  // XCD swizzle: 512 blocks = 8 XCDs x 64 contiguous q-tiles.
  const int id = blockIdx.x;
  const int lin = (id & 7) * 64 + (id >> 3);
  const int qt = lin & 31, h = (lin >> 5) & 7, b = lin >> 8;

  const int tid = threadIdx.x, lane = tid & 63, w = tid >> 6;
  const int l16 = lane & 15, lg = lane >> 4;
  const int q0 = qt * 64;
  const int qg = w & 3, half = w >> 2;
  const int wq = qg * 16;          // wave-owned q rows [wq, wq+16)
  const int kh0 = half * 64;       // wave-owned key half within the 128-key tile

  if (tid < 32) sBiasH[tid] = relb[tid * NH + h] * LOG2E;  // log2 units

  bf16x8 qh[2], ql[2];
  #pragma unroll
  for (int ks = 0; ks < 2; ++ks) {
    size_t o = (size_t)(b * QLEN + q0 + wq + l16) * INNER + h * DKV + ks * 32 + lg * 8;
    qh[ks] = *reinterpret_cast<const bf16x8*>(&Qh[o]);
    ql[ks] = *reinterpret_cast<const bf16x8*>(&Ql[o]);
  }

  f32x4 acc[4] = {};
  float mrow[4], lpart[4];
  #pragma unroll
  for (int r = 0; r < 4; ++r) { mrow[r] = -INFINITY; lpart[r] = 0.f; }

  // hoisted per-thread staging addresses (advance by constants per iter)
  const int krow = tid >> 3, kc8 = (tid & 7) * 8;      // K: 128 rows x 64 cols
  const int vrow = tid >> 4, vc8 = (tid & 15) * 8;     // V: 64 rows x 128 cols
  const bf16_t* kPtr = Kh + (size_t)(b * QLEN + krow) * INNER + h * DKV + kc8;
  const bf16_t* vPtr = Vt + (size_t)((b * NH + h) * DKV + vrow) * QLEN + vc8;
  const size_t kStep = (size_t)64 * INNER;             // +64 rows within a tile
  bf16_t* kDst0 = &sKh[krow * 72 + kc8];
  bf16_t* kDst1 = &sKh[(krow + 64) * 72 + kc8];
  bf16_t* vDst0 = &sV[vrow * SVS + vc8];
  bf16_t* vDst1 = &sV[(vrow + 32) * SVS + vc8 + 0];    // second V chunk: rows 32..63

  bf16x8 rk0, rk1, rv0, rv1;
  rk0 = *reinterpret_cast<const bf16x8*>(kPtr);
  rk1 = *reinterpret_cast<const bf16x8*>(kPtr + kStep);
  rv0 = *reinterpret_cast<const bf16x8*>(vPtr);
  rv1 = *reinterpret_cast<const bf16x8*>(vPtr + (size_t)32 * QLEN);
  *reinterpret_cast<bf16x8*>(kDst0) = rk0;
  *reinterpret_cast<bf16x8*>(kDst1) = rk1;
  *reinterpret_cast<bf16x8*>(vDst0) = rv0;
  *reinterpret_cast<bf16x8*>(vDst1) = rv1;
  __syncthreads();

  const int NT = QLEN / 128;   // 16
  for (int kt = 0; kt < NT; ++kt) {
    const int k0 = kt * 128;
    const bool pf = (kt + 1 < NT);
    if (pf) {   // issue next-tile loads; latency hides under compute
      const bf16_t* kp = kPtr + (size_t)(k0 + 128) * INNER;
      const bf16_t* vp = vPtr + k0 + 128;
      rk0 = *reinterpret_cast<const bf16x8*>(kp);
      rk1 = *reinterpret_cast<const bf16x8*>(kp + kStep);
      rv0 = *reinterpret_cast<const bf16x8*>(vp);
      rv1 = *reinterpret_cast<const bf16x8*>(vp + (size_t)32 * QLEN);
    }

    // S = Q K^T over this wave's 64 keys, 2 passes (qh*kh + ql*kh)
    f32x4 s[4] = {};
    __builtin_amdgcn_s_setprio(1);
    #pragma unroll
    for (int ks = 0; ks < 2; ++ks) {
      bf16x8 kf[4];
      #pragma unroll
      for (int ni = 0; ni < 4; ++ni)
        kf[ni] = *reinterpret_cast<const bf16x8*>(
            &sKh[(kh0 + ni * 16 + l16) * 72 + ks * 32 + lg * 8]);
      #pragma unroll
      for (int ni = 0; ni < 4; ++ni) {
        s[ni] = __builtin_amdgcn_mfma_f32_16x16x32_bf16(qh[ks], kf[ni], s[ni], 0, 0, 0);
        s[ni] = __builtin_amdgcn_mfma_f32_16x16x32_bf16(ql[ks], kf[ni], s[ni], 0, 0, 0);
      }
    }
    __builtin_amdgcn_s_setprio(0);

    // bias: wave's key span is [kbase, kbase+64)
    const int kbase = k0 + kh0;
    const int dmin = q0 - (kbase + 63);
    const int dmax = q0 + 63 - kbase;
    const bool farP = dmin >= 91, farN = dmax <= -91;
    float fbias = 0.f;
    if (farP) fbias = sBiasH[15];
    else if (farN) fbias = sBiasH[31];
    else {
      #pragma unroll
      for (int ni = 0; ni < 4; ++ni) {
        int kcol = kbase + ni * 16 + l16;
        #pragma unroll
        for (int r = 0; r < 4; ++r) {
          int qrow = q0 + wq + lg * 4 + r;
          int d = qrow - kcol;
          int n = d < 0 ? -d : d;
          int bk = t5_bucket_abs(n) + (d < 0 ? 16 : 0);
          s[ni][r] += sBiasH[bk];
        }
      }
    }

    // defer-max online softmax: cheap wave-vote, rare rescale
    float c[4], tmx[4];
    #pragma unroll
    for (int r = 0; r < 4; ++r) {
      tmx[r] = fmaxf(fmaxf(s[0][r], s[1][r]), fmaxf(s[2][r], s[3][r]));
      c[r] = mrow[r] - fbias;
    }
    float u = fmaxf(fmaxf(tmx[0] - c[0], tmx[1] - c[1]), fmaxf(tmx[2] - c[2], tmx[3] - c[3]));
    if (__any(u > THR_LOG2)) {
      #pragma unroll
      for (int r = 0; r < 4; ++r) {
        float rm = redmax16(tmx[r]) + fbias;
        float mnew = fmaxf(mrow[r], rm);
        float alpha = exp2f(mrow[r] - mnew);
        mrow[r] = mnew;
        c[r] = mnew - fbias;
        lpart[r] *= alpha;
        #pragma unroll
        for (int di = 0; di < 4; ++di) acc[di][r] *= alpha;
      }
    }

    // P = exp2(s - c); lane-local l partials; P -> LDS (wave-private 16x64 block)
    #pragma unroll
    for (int r = 0; r < 4; ++r) {
      float ps = 0.f;
      #pragma unroll
      for (int ni = 0; ni < 4; ++ni) {
        float p = exp2f(s[ni][r] - c[r]);
        ps += p;
        sP[half][(wq + lg * 4 + r) * SPS + ni * 16 + l16] = (bf16_t)p;
      }
      lpart[r] += ps;
    }

    // acc += P * V  (this wave's 64 keys)
    __builtin_amdgcn_s_setprio(1);
    #pragma unroll
    for (int ks = 0; ks < 2; ++ks) {
      bf16x8 pfr, vf[4];
      pfr = *reinterpret_cast<const bf16x8*>(&sP[half][(wq + l16) * SPS + ks * 32 + lg * 8]);
      #pragma unroll
      for (int di = 0; di < 4; ++di)
        vf[di] = *reinterpret_cast<const bf16x8*>(
            &sV[(di * 16 + l16) * SVS + kh0 + ks * 32 + lg * 8]);
      #pragma unroll
      for (int di = 0; di < 4; ++di)
        acc[di] = __builtin_amdgcn_mfma_f32_16x16x32_bf16(pfr, vf[di], acc[di], 0, 0, 0);
    }
    __builtin_amdgcn_s_setprio(0);

    __syncthreads();                 // all waves done reading this tile
    if (pf) {
      *reinterpret_cast<bf16x8*>(kDst0) = rk0;
      *reinterpret_cast<bf16x8*>(kDst1) = rk1;
      *reinterpret_cast<bf16x8*>(vDst0) = rv0;
      *reinterpret_cast<bf16x8*>(vDst1) = rv1;
    }
    __syncthreads();                 // next tile visible
  }

  // ----- merge the two key-halves (LSE combine) -----
  float lrow[4];
  #pragma unroll
  for (int r = 0; r < 4; ++r) lrow[r] = redsum16(lpart[r]);

  if (l16 == 0) {
    #pragma unroll
    for (int r = 0; r < 4; ++r) {
      int row = wq + lg * 4 + r;
      sM[half][row] = mrow[r];
      sL[half][row] = lrow[r];
    }
  }
  __syncthreads();

  float eh[4], denom[4];
  #pragma unroll
  for (int r = 0; r < 4; ++r) {
    int row = wq + lg * 4 + r;
    float m0 = sM[0][row], m1 = sM[1][row];
    float l0 = sL[0][row], l1 = sL[1][row];
    float M = fmaxf(m0, m1);
    float e0 = exp2f(m0 - M), e1 = exp2f(m1 - M);
    denom[r] = l0 * e0 + l1 * e1;
    eh[r] = half ? e1 : e0;
  }

  if (half == 1) {    // sAcc aliases sP: all sP reads completed before last barrier
    #pragma unroll
    for (int di = 0; di < 4; ++di)
      #pragma unroll
      for (int r = 0; r < 4; ++r)
        sAcc[(wq + lg * 4 + r) * SPS + di * 16 + l16] = acc[di][r] * eh[r];
  }
  __syncthreads();

  if (half == 0) {
    #pragma unroll
    for (int di = 0; di < 4; ++di)
      #pragma unroll
      for (int r = 0; r < 4; ++r) {
        int row = wq + lg * 4 + r;
        float v = (acc[di][r] * eh[r] + sAcc[row * SPS + di * 16 + l16]) / denom[r];
        ctx[(size_t)(b * QLEN + q0 + row) * INNER + h * DKV + di * 16 + l16] = (bf16_t)v;
      }
  }
}

extern "C" void kernel_launch(void* const* d_in, const int* in_sizes, int n_in,
                              void* d_out, int out_size, void* d_ws, size_t ws_size,
                              hipStream_t stream) {
  const float* X    = (const float*)d_in[0];
  const float* Wq   = (const float*)d_in[1];
  const float* Wk   = (const float*)d_in[2];
  const float* Wv   = (const float*)d_in[3];
  const float* Wo   = (const float*)d_in[4];
  const float* relb = (const float*)d_in[5];
  float* out = (float*)d_out;

  const size_t WSZ = 262144, XSZ = 2097152;
  bf16_t* ws   = (bf16_t*)d_ws;
  bf16_t* Wq_h = ws;              bf16_t* Wq_l = Wq_h + WSZ;
  bf16_t* Wk_h = Wq_l + WSZ;      bf16_t* Wk_l = Wk_h + WSZ;
  bf16_t* Wv_h = Wk_l + WSZ;      bf16_t* Wv_l = Wv_h + WSZ;
  bf16_t* Wo_h = Wv_l + WSZ;      bf16_t* Wo_l = Wo_h + WSZ;
  bf16_t* buf0 = Wo_l + WSZ;      bf16_t* buf1 = buf0 + XSZ;
  bf16_t* Q_h  = buf1 + XSZ;      bf16_t* Q_l  = Q_h + XSZ;
  bf16_t* K_h  = Q_l + XSZ;
  bf16_t* Vt   = buf1;            // V^T [b][h*64+d][s]
  bf16_t* ctx  = buf0;            // attention output

  transpose512_split_all<<<dim3(16, 16, 4), dim3(32, 8), 0, stream>>>(
      Wq, Wk, Wv, Wo, Wq_h, Wq_l, Wk_h, Wk_l, Wv_h, Wv_l, Wo_h, Wo_l);

  gemm_qkv<<<dim3(64, 12), 256, 0, stream>>>(X, Wq_h, Wq_l, Wk_h, Wk_l, Wv_h,
                                             Q_h, Q_l, K_h, Vt);

  attn_kernel<<<dim3(512), 512, 0, stream>>>(Q_h, Q_l, K_h, Vt, relb, ctx);

  gemm_out<<<dim3(64, 8), 256, 0, stream>>>(ctx, Wo_h, out);
}

// Round 16
// 105.736 us; speedup vs baseline: 1.1219x; 1.1219x over previous
//
#include <hip/hip_runtime.h>
#include <hip/hip_bf16.h>
#include <cmath>

typedef __bf16 bf16_t;
typedef __bf16 bf16x8 __attribute__((ext_vector_type(8)));
typedef __bf16 bf16x4 __attribute__((ext_vector_type(4)));
typedef float f32x4 __attribute__((ext_vector_type(4)));

#define QLEN 2048
#define DMODEL 512
#define NH 8
#define DKV 64
#define INNER 512
#define LOG2E 1.44269504f
#define THR_LOG2 11.5415603f   // 8 * log2(e)

// ---------- prep: 4 weight transposes fused: Wt[n][k] = W[k][n], hi/lo split ----------
__global__ __launch_bounds__(256) void transpose512_split_all(
    const float* __restrict__ W0, const float* __restrict__ W1,
    const float* __restrict__ W2, const float* __restrict__ W3,
    bf16_t* __restrict__ H0, bf16_t* __restrict__ L0,
    bf16_t* __restrict__ H1, bf16_t* __restrict__ L1,
    bf16_t* __restrict__ H2, bf16_t* __restrict__ L2,
    bf16_t* __restrict__ H3, bf16_t* __restrict__ L3) {
  __shared__ float tile[32][33];
  int z = blockIdx.z;
  const float* W = z == 0 ? W0 : z == 1 ? W1 : z == 2 ? W2 : W3;
  bf16_t* Whi    = z == 0 ? H0 : z == 1 ? H1 : z == 2 ? H2 : H3;
  bf16_t* Wlo    = z == 0 ? L0 : z == 1 ? L1 : z == 2 ? L2 : L3;
  int bk = blockIdx.x * 32, bn = blockIdx.y * 32;
  int tx = threadIdx.x, ty = threadIdx.y;
  #pragma unroll
  for (int i = 0; i < 32; i += 8)
    tile[ty + i][tx] = W[(size_t)(bk + ty + i) * DMODEL + bn + tx];
  __syncthreads();
  #pragma unroll
  for (int i = 0; i < 32; i += 8) {
    float v = tile[tx][ty + i];
    bf16_t hb = (bf16_t)v;
    size_t o = (size_t)(bn + ty + i) * DMODEL + bk + tx;
    Whi[o] = hb;
    Wlo[o] = (bf16_t)(v - (float)hb);
  }
}

// ---------- helpers ----------
__device__ __forceinline__ void splitx8(const float4& v0, const float4& v1,
                                        bf16x8& h, bf16x8& l) {
  #pragma unroll
  for (int j = 0; j < 4; ++j) {
    float x = (&v0.x)[j];
    bf16_t hb = (bf16_t)x;
    h[j] = hb; l[j] = (bf16_t)(x - (float)hb);
  }
  #pragma unroll
  for (int j = 0; j < 4; ++j) {
    float x = (&v1.x)[j];
    bf16_t hb = (bf16_t)x;
    h[4 + j] = hb; l[4 + j] = (bf16_t)(x - (float)hb);
  }
}
__device__ __forceinline__ bf16x8 castx8(const float4& v0, const float4& v1) {
  bf16x8 h;
  #pragma unroll
  for (int j = 0; j < 4; ++j) h[j] = (bf16_t)(&v0.x)[j];
  #pragma unroll
  for (int j = 0; j < 4; ++j) h[4 + j] = (bf16_t)(&v1.x)[j];
  return h;
}

#define GST 72

// ---------- single-pass bf16 GEMM, BM=BN=64 ----------
// AF32: A read as f32 and cast-hi during staging (V projection).
// MODE 1: bf16 transposed (V): C[(b*512+n)*2048+s]; MODE 2: f32 natural.
template<int MODE, int AF32>
__global__ __launch_bounds__(256) void gemm64(const bf16_t* __restrict__ Ab,
                                              const float* __restrict__ Af,
                                              const bf16_t* __restrict__ Bt,
                                              bf16_t* __restrict__ Cb,
                                              float* __restrict__ Cf) {
  __shared__ bf16_t sA[64 * GST];
  __shared__ bf16_t sB[64 * GST];
  const int m0 = blockIdx.x * 64, n0 = blockIdx.y * 64;
  const int tid = threadIdx.x;
  const int lane = tid & 63, w = tid >> 6;
  const int wr = (w >> 1) * 32, wc = (w & 1) * 32;
  const int l16 = lane & 15, lg = lane >> 4;

  f32x4 acc[2][2] = {};

  for (int k0 = 0; k0 < DMODEL; k0 += 64) {
    #pragma unroll
    for (int i = 0; i < 2; ++i) {
      int chunk = tid + i * 256;
      int row = chunk >> 3, c8 = (chunk & 7) * 8;
      if (AF32) {
        const float4* src = reinterpret_cast<const float4*>(
            &Af[(size_t)(m0 + row) * DMODEL + k0 + c8]);
        *reinterpret_cast<bf16x8*>(&sA[row * GST + c8]) = castx8(src[0], src[1]);
      } else {
        *reinterpret_cast<bf16x8*>(&sA[row * GST + c8]) =
            *reinterpret_cast<const bf16x8*>(&Ab[(size_t)(m0 + row) * DMODEL + k0 + c8]);
      }
      *reinterpret_cast<bf16x8*>(&sB[row * GST + c8]) =
          *reinterpret_cast<const bf16x8*>(&Bt[(size_t)(n0 + row) * DMODEL + k0 + c8]);
    }
    __syncthreads();
    #pragma unroll
    for (int ks = 0; ks < 2; ++ks) {
      bf16x8 af[2], bfr[2];
      #pragma unroll
      for (int i = 0; i < 2; ++i)
        af[i] = *reinterpret_cast<const bf16x8*>(&sA[(wr + i * 16 + l16) * GST + ks * 32 + lg * 8]);
      #pragma unroll
      for (int j = 0; j < 2; ++j)
        bfr[j] = *reinterpret_cast<const bf16x8*>(&sB[(wc + j * 16 + l16) * GST + ks * 32 + lg * 8]);
      #pragma unroll
      for (int i = 0; i < 2; ++i)
        #pragma unroll
        for (int j = 0; j < 2; ++j)
          acc[i][j] = __builtin_amdgcn_mfma_f32_16x16x32_bf16(af[i], bfr[j], acc[i][j], 0, 0, 0);
    }
    __syncthreads();
  }

  #pragma unroll
  for (int i = 0; i < 2; ++i)
    #pragma unroll
    for (int j = 0; j < 2; ++j)
      #pragma unroll
      for (int r = 0; r < 4; ++r) {
        int m = m0 + wr + i * 16 + lg * 4 + r;
        int n = n0 + wc + j * 16 + l16;
        float v = acc[i][j][r];
        if (MODE == 1) {
          int b = m >> 11, s = m & (QLEN - 1);
          Cb[(size_t)(b * INNER + n) * QLEN + s] = (bf16_t)v;
        } else {
          Cf[(size_t)m * DMODEL + n] = v;
        }
      }
}

// ---------- fused Q+K 3-pass split GEMM: BM=64, BN=64, grid (64,16) ----------
// y<8: Q (n0=y*64, *log2e, hi/lo out); y>=8: K (hi out). LDS 36.9KB -> 4 blocks/CU.
__global__ __launch_bounds__(256) void gemm_qk_split(const float* __restrict__ X,
                                                     const bf16_t* __restrict__ Bqh,
                                                     const bf16_t* __restrict__ Bql,
                                                     const bf16_t* __restrict__ Bkh,
                                                     const bf16_t* __restrict__ Bkl,
                                                     bf16_t* __restrict__ Qh,
                                                     bf16_t* __restrict__ Ql,
                                                     bf16_t* __restrict__ Kh) {
  __shared__ bf16_t sAh[64 * GST];
  __shared__ bf16_t sAl[64 * GST];
  __shared__ bf16_t sBh[64 * GST];
  __shared__ bf16_t sBl[64 * GST];
  const int m0 = blockIdx.x * 64;
  const int y = blockIdx.y;
  const bool isK = y >= 8;
  const int n0 = (y & 7) * 64;
  const bf16_t* __restrict__ Bh = isK ? Bkh : Bqh;
  const bf16_t* __restrict__ Bl = isK ? Bkl : Bql;

  const int tid = threadIdx.x;
  const int lane = tid & 63, w = tid >> 6;
  const int wr = (w >> 1) * 32, wc = (w & 1) * 32;
  const int l16 = lane & 15, lg = lane >> 4;

  f32x4 acc[2][2] = {};

  for (int k0 = 0; k0 < DMODEL; k0 += 64) {
    #pragma unroll
    for (int i = 0; i < 2; ++i) {
      int chunk = tid + i * 256;
      int row = chunk >> 3, c8 = (chunk & 7) * 8;
      const float4* src = reinterpret_cast<const float4*>(
          &X[(size_t)(m0 + row) * DMODEL + k0 + c8]);
      bf16x8 h, l;
      splitx8(src[0], src[1], h, l);
      *reinterpret_cast<bf16x8*>(&sAh[row * GST + c8]) = h;
      *reinterpret_cast<bf16x8*>(&sAl[row * GST + c8]) = l;
      size_t gb = (size_t)(n0 + row) * DMODEL + k0 + c8;
      *reinterpret_cast<bf16x8*>(&sBh[row * GST + c8]) = *reinterpret_cast<const bf16x8*>(&Bh[gb]);
      *reinterpret_cast<bf16x8*>(&sBl[row * GST + c8]) = *reinterpret_cast<const bf16x8*>(&Bl[gb]);
    }
    __syncthreads();
    #pragma unroll
    for (int ks = 0; ks < 2; ++ks) {
      bf16x8 ah[2], al[2], bh[2], bl[2];
      #pragma unroll
      for (int i = 0; i < 2; ++i) {
        int ro = (wr + i * 16 + l16) * GST + ks * 32 + lg * 8;
        ah[i] = *reinterpret_cast<const bf16x8*>(&sAh[ro]);
        al[i] = *reinterpret_cast<const bf16x8*>(&sAl[ro]);
      }
      #pragma unroll
      for (int j = 0; j < 2; ++j) {
        int ro = (wc + j * 16 + l16) * GST + ks * 32 + lg * 8;
        bh[j] = *reinterpret_cast<const bf16x8*>(&sBh[ro]);
        bl[j] = *reinterpret_cast<const bf16x8*>(&sBl[ro]);
      }
      #pragma unroll
      for (int i = 0; i < 2; ++i)
        #pragma unroll
        for (int j = 0; j < 2; ++j) {
          acc[i][j] = __builtin_amdgcn_mfma_f32_16x16x32_bf16(ah[i], bh[j], acc[i][j], 0, 0, 0);
          acc[i][j] = __builtin_amdgcn_mfma_f32_16x16x32_bf16(ah[i], bl[j], acc[i][j], 0, 0, 0);
          acc[i][j] = __builtin_amdgcn_mfma_f32_16x16x32_bf16(al[i], bh[j], acc[i][j], 0, 0, 0);
        }
    }
    __syncthreads();
  }

  #pragma unroll
  for (int i = 0; i < 2; ++i)
    #pragma unroll
    for (int j = 0; j < 2; ++j)
      #pragma unroll
      for (int r = 0; r < 4; ++r) {
        int m = m0 + wr + i * 16 + lg * 4 + r;
        int n = n0 + wc + j * 16 + l16;
        float v = acc[i][j][r];
        if (!isK) {
          v *= LOG2E;
          bf16_t hb = (bf16_t)v;
          size_t o = (size_t)m * INNER + n;
          Qh[o] = hb;
          Ql[o] = (bf16_t)(v - (float)hb);
        } else {
          Kh[(size_t)m * INNER + n] = (bf16_t)v;
        }
      }
}

// ---------- attention helpers ----------
__device__ __forceinline__ float redmax16(float v) {
  v = fmaxf(v, __shfl_xor(v, 1));
  v = fmaxf(v, __shfl_xor(v, 2));
  v = fmaxf(v, __shfl_xor(v, 4));
  v = fmaxf(v, __shfl_xor(v, 8));
  return v;
}
__device__ __forceinline__ float redsum16(float v) {
  v += __shfl_xor(v, 1);
  v += __shfl_xor(v, 2);
  v += __shfl_xor(v, 4);
  v += __shfl_xor(v, 8);
  return v;
}
__device__ __forceinline__ int t5_bucket_abs(int n) {
  if (n < 8)  return n;
  if (n < 12) return 8;
  if (n < 16) return 9;
  if (n < 23) return 10;
  if (n < 32) return 11;
  if (n < 46) return 12;
  if (n < 64) return 13;
  if (n < 91) return 14;
  return 15;
}

// ---------- flash attention (R9/R14 structure, hoisted staging addresses) ----------
#define SPS 68    // sP row stride (bf16) and sAcc row stride (f32)
#define SVS 136   // sV row stride (bf16)

__global__ __launch_bounds__(512, 4) void attn_kernel(const bf16_t* __restrict__ Qh,
                                                      const bf16_t* __restrict__ Ql,
                                                      const bf16_t* __restrict__ Kh,
                                                      const bf16_t* __restrict__ Vt,
                                                      const float* __restrict__ relb,
                                                      bf16_t* __restrict__ ctx) {
  __shared__ bf16_t sKh[128 * 72];        // 18432 B
  __shared__ bf16_t sV [64 * SVS];        // 17408 B
  __shared__ bf16_t sP [2][64 * SPS];     // 17408 B (aliased as f32 sAcc in merge)
  __shared__ float sM[2][64], sL[2][64];  // 1024 B
  __shared__ float sBiasH[32];
  float* sAcc = (float*)&sP[0][0];

  // XCD swizzle: 512 blocks = 8 XCDs x 64 contiguous q-tiles.
  const int id = blockIdx.x;
  const int lin = (id & 7) * 64 + (id >> 3);
  const int qt = lin & 31, h = (lin >> 5) & 7, b = lin >> 8;

  const int tid = threadIdx.x, lane = tid & 63, w = tid >> 6;
  const int l16 = lane & 15, lg = lane >> 4;
  const int q0 = qt * 64;
  const int qg = w & 3, half = w >> 2;
  const int wq = qg * 16;          // wave-owned q rows [wq, wq+16)
  const int kh0 = half * 64;       // wave-owned key half within the 128-key tile

  if (tid < 32) sBiasH[tid] = relb[tid * NH + h] * LOG2E;  // log2 units

  bf16x8 qh[2], ql[2];
  #pragma unroll
  for (int ks = 0; ks < 2; ++ks) {
    size_t o = (size_t)(b * QLEN + q0 + wq + l16) * INNER + h * DKV + ks * 32 + lg * 8;
    qh[ks] = *reinterpret_cast<const bf16x8*>(&Qh[o]);
    ql[ks] = *reinterpret_cast<const bf16x8*>(&Ql[o]);
  }

  f32x4 acc[4] = {};
  float mrow[4], lpart[4];
  #pragma unroll
  for (int r = 0; r < 4; ++r) { mrow[r] = -INFINITY; lpart[r] = 0.f; }

  // hoisted per-thread staging addresses (advance by constants per iter)
  const int krow = tid >> 3, kc8 = (tid & 7) * 8;      // K: 128 rows x 64 cols
  const int vrow = tid >> 4, vc8 = (tid & 15) * 8;     // V: 64 rows x 128 cols
  const bf16_t* kPtr = Kh + (size_t)(b * QLEN + krow) * INNER + h * DKV + kc8;
  const bf16_t* vPtr = Vt + (size_t)((b * NH + h) * DKV + vrow) * QLEN + vc8;
  const size_t kStep = (size_t)64 * INNER;
  bf16_t* kDst0 = &sKh[krow * 72 + kc8];
  bf16_t* kDst1 = &sKh[(krow + 64) * 72 + kc8];
  bf16_t* vDst0 = &sV[vrow * SVS + vc8];
  bf16_t* vDst1 = &sV[(vrow + 32) * SVS + vc8];

  bf16x8 rk0, rk1, rv0, rv1;
  rk0 = *reinterpret_cast<const bf16x8*>(kPtr);
  rk1 = *reinterpret_cast<const bf16x8*>(kPtr + kStep);
  rv0 = *reinterpret_cast<const bf16x8*>(vPtr);
  rv1 = *reinterpret_cast<const bf16x8*>(vPtr + (size_t)32 * QLEN);
  *reinterpret_cast<bf16x8*>(kDst0) = rk0;
  *reinterpret_cast<bf16x8*>(kDst1) = rk1;
  *reinterpret_cast<bf16x8*>(vDst0) = rv0;
  *reinterpret_cast<bf16x8*>(vDst1) = rv1;
  __syncthreads();

  const int NT = QLEN / 128;   // 16
  for (int kt = 0; kt < NT; ++kt) {
    const int k0 = kt * 128;
    const bool pf = (kt + 1 < NT);
    if (pf) {
      const bf16_t* kp = kPtr + (size_t)(k0 + 128) * INNER;
      const bf16_t* vp = vPtr + k0 + 128;
      rk0 = *reinterpret_cast<const bf16x8*>(kp);
      rk1 = *reinterpret_cast<const bf16x8*>(kp + kStep);
      rv0 = *reinterpret_cast<const bf16x8*>(vp);
      rv1 = *reinterpret_cast<const bf16x8*>(vp + (size_t)32 * QLEN);
    }

    // S = Q K^T over this wave's 64 keys, 2 passes (qh*kh + ql*kh)
    f32x4 s[4] = {};
    __builtin_amdgcn_s_setprio(1);
    #pragma unroll
    for (int ks = 0; ks < 2; ++ks) {
      bf16x8 kf[4];
      #pragma unroll
      for (int ni = 0; ni < 4; ++ni)
        kf[ni] = *reinterpret_cast<const bf16x8*>(
            &sKh[(kh0 + ni * 16 + l16) * 72 + ks * 32 + lg * 8]);
      #pragma unroll
      for (int ni = 0; ni < 4; ++ni) {
        s[ni] = __builtin_amdgcn_mfma_f32_16x16x32_bf16(qh[ks], kf[ni], s[ni], 0, 0, 0);
        s[ni] = __builtin_amdgcn_mfma_f32_16x16x32_bf16(ql[ks], kf[ni], s[ni], 0, 0, 0);
      }
    }
    __builtin_amdgcn_s_setprio(0);

    // bias: wave's key span is [kbase, kbase+64)
    const int kbase = k0 + kh0;
    const int dmin = q0 - (kbase + 63);
    const int dmax = q0 + 63 - kbase;
    const bool farP = dmin >= 91, farN = dmax <= -91;
    float fbias = 0.f;
    if (farP) fbias = sBiasH[15];
    else if (farN) fbias = sBiasH[31];
    else {
      #pragma unroll
      for (int ni = 0; ni < 4; ++ni) {
        int kcol = kbase + ni * 16 + l16;
        #pragma unroll
        for (int r = 0; r < 4; ++r) {
          int qrow = q0 + wq + lg * 4 + r;
          int d = qrow - kcol;
          int n = d < 0 ? -d : d;
          int bk = t5_bucket_abs(n) + (d < 0 ? 16 : 0);
          s[ni][r] += sBiasH[bk];
        }
      }
    }

    // defer-max online softmax: cheap wave-vote, rare rescale
    float c[4], tmx[4];
    #pragma unroll
    for (int r = 0; r < 4; ++r) {
      tmx[r] = fmaxf(fmaxf(s[0][r], s[1][r]), fmaxf(s[2][r], s[3][r]));
      c[r] = mrow[r] - fbias;
    }
    float u = fmaxf(fmaxf(tmx[0] - c[0], tmx[1] - c[1]), fmaxf(tmx[2] - c[2], tmx[3] - c[3]));
    if (__any(u > THR_LOG2)) {
      #pragma unroll
      for (int r = 0; r < 4; ++r) {
        float rm = redmax16(tmx[r]) + fbias;
        float mnew = fmaxf(mrow[r], rm);
        float alpha = exp2f(mrow[r] - mnew);
        mrow[r] = mnew;
        c[r] = mnew - fbias;
        lpart[r] *= alpha;
        #pragma unroll
        for (int di = 0; di < 4; ++di) acc[di][r] *= alpha;
      }
    }

    // P = exp2(s - c); lane-local l partials; P -> LDS (wave-private 16x64 block)
    #pragma unroll
    for (int r = 0; r < 4; ++r) {
      float ps = 0.f;
      #pragma unroll
      for (int ni = 0; ni < 4; ++ni) {
        float p = exp2f(s[ni][r] - c[r]);
        ps += p;
        sP[half][(wq + lg * 4 + r) * SPS + ni * 16 + l16] = (bf16_t)p;
      }
      lpart[r] += ps;
    }

    // acc += P * V  (this wave's 64 keys)
    __builtin_amdgcn_s_setprio(1);
    #pragma unroll
    for (int ks = 0; ks < 2; ++ks) {
      bf16x8 pfr, vf[4];
      pfr = *reinterpret_cast<const bf16x8*>(&sP[half][(wq + l16) * SPS + ks * 32 + lg * 8]);
      #pragma unroll
      for (int di = 0; di < 4; ++di)
        vf[di] = *reinterpret_cast<const bf16x8*>(
            &sV[(di * 16 + l16) * SVS + kh0 + ks * 32 + lg * 8]);
      #pragma unroll
      for (int di = 0; di < 4; ++di)
        acc[di] = __builtin_amdgcn_mfma_f32_16x16x32_bf16(pfr, vf[di], acc[di], 0, 0, 0);
    }
    __builtin_amdgcn_s_setprio(0);

    __syncthreads();                 // all waves done reading this tile
    if (pf) {
      *reinterpret_cast<bf16x8*>(kDst0) = rk0;
      *reinterpret_cast<bf16x8*>(kDst1) = rk1;
      *reinterpret_cast<bf16x8*>(vDst0) = rv0;
      *reinterpret_cast<bf16x8*>(vDst1) = rv1;
    }
    __syncthreads();                 // next tile visible
  }

  // ----- merge the two key-halves (LSE combine) -----
  float lrow[4];
  #pragma unroll
  for (int r = 0; r < 4; ++r) lrow[r] = redsum16(lpart[r]);

  if (l16 == 0) {
    #pragma unroll
    for (int r = 0; r < 4; ++r) {
      int row = wq + lg * 4 + r;
      sM[half][row] = mrow[r];
      sL[half][row] = lrow[r];
    }
  }
  __syncthreads();

  float eh[4], denom[4];
  #pragma unroll
  for (int r = 0; r < 4; ++r) {
    int row = wq + lg * 4 + r;
    float m0 = sM[0][row], m1 = sM[1][row];
    float l0 = sL[0][row], l1 = sL[1][row];
    float M = fmaxf(m0, m1);
    float e0 = exp2f(m0 - M), e1 = exp2f(m1 - M);
    denom[r] = l0 * e0 + l1 * e1;
    eh[r] = half ? e1 : e0;
  }

  if (half == 1) {    // sAcc aliases sP: all sP reads completed before last barrier
    #pragma unroll
    for (int di = 0; di < 4; ++di)
      #pragma unroll
      for (int r = 0; r < 4; ++r)
        sAcc[(wq + lg * 4 + r) * SPS + di * 16 + l16] = acc[di][r] * eh[r];
  }
  __syncthreads();

  if (half == 0) {
    #pragma unroll
    for (int di = 0; di < 4; ++di)
      #pragma unroll
      for (int r = 0; r < 4; ++r) {
        int row = wq + lg * 4 + r;
        float v = (acc[di][r] * eh[r] + sAcc[row * SPS + di * 16 + l16]) / denom[r];
        ctx[(size_t)(b * QLEN + q0 + row) * INNER + h * DKV + di * 16 + l16] = (bf16_t)v;
      }
  }
}

extern "C" void kernel_launch(void* const* d_in, const int* in_sizes, int n_in,
                              void* d_out, int out_size, void* d_ws, size_t ws_size,
                              hipStream_t stream) {
  const float* X    = (const float*)d_in[0];
  const float* Wq   = (const float*)d_in[1];
  const float* Wk   = (const float*)d_in[2];
  const float* Wv   = (const float*)d_in[3];
  const float* Wo   = (const float*)d_in[4];
  const float* relb = (const float*)d_in[5];
  float* out = (float*)d_out;

  const size_t WSZ = 262144, XSZ = 2097152;
  bf16_t* ws   = (bf16_t*)d_ws;
  bf16_t* Wq_h = ws;              bf16_t* Wq_l = Wq_h + WSZ;
  bf16_t* Wk_h = Wq_l + WSZ;      bf16_t* Wk_l = Wk_h + WSZ;
  bf16_t* Wv_h = Wk_l + WSZ;      bf16_t* Wv_l = Wv_h + WSZ;
  bf16_t* Wo_h = Wv_l + WSZ;      bf16_t* Wo_l = Wo_h + WSZ;
  bf16_t* buf0 = Wo_l + WSZ;      bf16_t* buf1 = buf0 + XSZ;
  bf16_t* Q_h  = buf1 + XSZ;      bf16_t* Q_l  = Q_h + XSZ;
  bf16_t* K_h  = Q_l + XSZ;
  bf16_t* Vt   = buf1;            // V^T [b][h*64+d][s]
  bf16_t* ctx  = buf0;            // attention output

  transpose512_split_all<<<dim3(16, 16, 4), dim3(32, 8), 0, stream>>>(
      Wq, Wk, Wv, Wo, Wq_h, Wq_l, Wk_h, Wk_l, Wv_h, Wv_l, Wo_h, Wo_l);

  gemm_qk_split<<<dim3(64, 16), 256, 0, stream>>>(X, Wq_h, Wq_l, Wk_h, Wk_l,
                                                  Q_h, Q_l, K_h);
  gemm64<1, 1><<<dim3(64, 8), 256, 0, stream>>>(nullptr, X, Wv_h, Vt, nullptr);

  attn_kernel<<<dim3(512), 512, 0, stream>>>(Q_h, Q_l, K_h, Vt, relb, ctx);

  gemm64<2, 0><<<dim3(64, 8), 256, 0, stream>>>(ctx, nullptr, Wo_h, nullptr, out);
}

// Round 17
// 103.537 us; speedup vs baseline: 1.1458x; 1.0212x over previous
//
#include <hip/hip_runtime.h>
#include <hip/hip_bf16.h>
#include <cmath>

typedef __bf16 bf16_t;
typedef __bf16 bf16x8 __attribute__((ext_vector_type(8)));
typedef __bf16 bf16x4 __attribute__((ext_vector_type(4)));
typedef float f32x4 __attribute__((ext_vector_type(4)));

#define QLEN 2048
#define DMODEL 512
#define NH 8
#define DKV 64
#define INNER 512
#define LOG2E 1.44269504f
#define THR_LOG2 11.5415603f   // 8 * log2(e)

// ---------- prep: 4 weight transposes fused: Wt[n][k] = W[k][n], hi/lo split ----------
__global__ __launch_bounds__(256) void transpose512_split_all(
    const float* __restrict__ W0, const float* __restrict__ W1,
    const float* __restrict__ W2, const float* __restrict__ W3,
    bf16_t* __restrict__ H0, bf16_t* __restrict__ L0,
    bf16_t* __restrict__ H1, bf16_t* __restrict__ L1,
    bf16_t* __restrict__ H2, bf16_t* __restrict__ L2,
    bf16_t* __restrict__ H3, bf16_t* __restrict__ L3) {
  __shared__ float tile[32][33];
  int z = blockIdx.z;
  const float* W = z == 0 ? W0 : z == 1 ? W1 : z == 2 ? W2 : W3;
  bf16_t* Whi    = z == 0 ? H0 : z == 1 ? H1 : z == 2 ? H2 : H3;
  bf16_t* Wlo    = z == 0 ? L0 : z == 1 ? L1 : z == 2 ? L2 : L3;
  int bk = blockIdx.x * 32, bn = blockIdx.y * 32;
  int tx = threadIdx.x, ty = threadIdx.y;
  #pragma unroll
  for (int i = 0; i < 32; i += 8)
    tile[ty + i][tx] = W[(size_t)(bk + ty + i) * DMODEL + bn + tx];
  __syncthreads();
  #pragma unroll
  for (int i = 0; i < 32; i += 8) {
    float v = tile[tx][ty + i];
    bf16_t hb = (bf16_t)v;
    size_t o = (size_t)(bn + ty + i) * DMODEL + bk + tx;
    Whi[o] = hb;
    Wlo[o] = (bf16_t)(v - (float)hb);
  }
}

// ---------- helpers ----------
__device__ __forceinline__ void splitx8(const float4& v0, const float4& v1,
                                        bf16x8& h, bf16x8& l) {
  #pragma unroll
  for (int j = 0; j < 4; ++j) {
    float x = (&v0.x)[j];
    bf16_t hb = (bf16_t)x;
    h[j] = hb; l[j] = (bf16_t)(x - (float)hb);
  }
  #pragma unroll
  for (int j = 0; j < 4; ++j) {
    float x = (&v1.x)[j];
    bf16_t hb = (bf16_t)x;
    h[4 + j] = hb; l[4 + j] = (bf16_t)(x - (float)hb);
  }
}

__device__ __forceinline__ int t5_bucket_abs(int n) {
  if (n < 8)  return n;
  if (n < 12) return 8;
  if (n < 16) return 9;
  if (n < 23) return 10;
  if (n < 32) return 11;
  if (n < 46) return 12;
  if (n < 64) return 13;
  if (n < 91) return 14;
  return 15;
}

#define GST 72

// ---------- fused Q+K+V projection: grid (64, 24), all at 36.9KB LDS class ----------
// kind = y>>3: 0=Q (3-pass, *log2e, hi/lo out), 1=K (3-pass, hi out),
//              2=V (1-pass, V^T out). A = X f32, split hi/lo during staging.
__global__ __launch_bounds__(256) void gemm_qkv(const float* __restrict__ X,
                                                const bf16_t* __restrict__ Wqh,
                                                const bf16_t* __restrict__ Wql,
                                                const bf16_t* __restrict__ Wkh,
                                                const bf16_t* __restrict__ Wkl,
                                                const bf16_t* __restrict__ Wvh,
                                                bf16_t* __restrict__ Qh,
                                                bf16_t* __restrict__ Ql,
                                                bf16_t* __restrict__ Kh,
                                                bf16_t* __restrict__ Vt) {
  __shared__ bf16_t sAh[64 * GST];
  __shared__ bf16_t sAl[64 * GST];
  __shared__ bf16_t sBh[64 * GST];
  __shared__ bf16_t sBl[64 * GST];
  const int m0 = blockIdx.x * 64;
  const int y = blockIdx.y;
  const int kind = y >> 3;             // 0=Q 1=K 2=V
  const int n0 = (y & 7) * 64;
  const bf16_t* __restrict__ Bh = kind == 0 ? Wqh : kind == 1 ? Wkh : Wvh;
  const bf16_t* __restrict__ Bl = kind == 0 ? Wql : Wkl;   // unused when kind==2

  const int tid = threadIdx.x;
  const int lane = tid & 63, w = tid >> 6;
  const int wr = (w >> 1) * 32, wc = (w & 1) * 32;
  const int l16 = lane & 15, lg = lane >> 4;

  f32x4 acc[2][2] = {};

  for (int k0 = 0; k0 < DMODEL; k0 += 64) {
    #pragma unroll
    for (int i = 0; i < 2; ++i) {
      int chunk = tid + i * 256;
      int row = chunk >> 3, c8 = (chunk & 7) * 8;
      const float4* src = reinterpret_cast<const float4*>(
          &X[(size_t)(m0 + row) * DMODEL + k0 + c8]);
      bf16x8 h, l;
      splitx8(src[0], src[1], h, l);
      *reinterpret_cast<bf16x8*>(&sAh[row * GST + c8]) = h;
      *reinterpret_cast<bf16x8*>(&sAl[row * GST + c8]) = l;
      size_t gb = (size_t)(n0 + row) * DMODEL + k0 + c8;
      *reinterpret_cast<bf16x8*>(&sBh[row * GST + c8]) = *reinterpret_cast<const bf16x8*>(&Bh[gb]);
      if (kind < 2)
        *reinterpret_cast<bf16x8*>(&sBl[row * GST + c8]) = *reinterpret_cast<const bf16x8*>(&Bl[gb]);
    }
    __syncthreads();
    #pragma unroll
    for (int ks = 0; ks < 2; ++ks) {
      bf16x8 ah[2], al[2], bh[2], bl[2];
      #pragma unroll
      for (int i = 0; i < 2; ++i) {
        int ro = (wr + i * 16 + l16) * GST + ks * 32 + lg * 8;
        ah[i] = *reinterpret_cast<const bf16x8*>(&sAh[ro]);
        al[i] = *reinterpret_cast<const bf16x8*>(&sAl[ro]);
      }
      #pragma unroll
      for (int j = 0; j < 2; ++j) {
        int ro = (wc + j * 16 + l16) * GST + ks * 32 + lg * 8;
        bh[j] = *reinterpret_cast<const bf16x8*>(&sBh[ro]);
        bl[j] = *reinterpret_cast<const bf16x8*>(&sBl[ro]);
      }
      #pragma unroll
      for (int i = 0; i < 2; ++i)
        #pragma unroll
        for (int j = 0; j < 2; ++j)
          acc[i][j] = __builtin_amdgcn_mfma_f32_16x16x32_bf16(ah[i], bh[j], acc[i][j], 0, 0, 0);
      if (kind < 2) {
        #pragma unroll
        for (int i = 0; i < 2; ++i)
          #pragma unroll
          for (int j = 0; j < 2; ++j) {
            acc[i][j] = __builtin_amdgcn_mfma_f32_16x16x32_bf16(ah[i], bl[j], acc[i][j], 0, 0, 0);
            acc[i][j] = __builtin_amdgcn_mfma_f32_16x16x32_bf16(al[i], bh[j], acc[i][j], 0, 0, 0);
          }
      }
    }
    __syncthreads();
  }

  #pragma unroll
  for (int i = 0; i < 2; ++i)
    #pragma unroll
    for (int j = 0; j < 2; ++j)
      #pragma unroll
      for (int r = 0; r < 4; ++r) {
        int m = m0 + wr + i * 16 + lg * 4 + r;
        int n = n0 + wc + j * 16 + l16;
        float v = acc[i][j][r];
        if (kind == 0) {
          v *= LOG2E;
          bf16_t hb = (bf16_t)v;
          size_t o = (size_t)m * INNER + n;
          Qh[o] = hb;
          Ql[o] = (bf16_t)(v - (float)hb);
        } else if (kind == 1) {
          Kh[(size_t)m * INNER + n] = (bf16_t)v;
        } else {
          int b = m >> 11, s = m & (QLEN - 1);
          Vt[(size_t)(b * INNER + n) * QLEN + s] = (bf16_t)v;
        }
      }
}

// ---------- output projection GEMM: BM=BN=64, f32 out ----------
__global__ __launch_bounds__(256) void gemm_out(const bf16_t* __restrict__ A,
                                                const bf16_t* __restrict__ Bt,
                                                float* __restrict__ Cf) {
  __shared__ bf16_t sA[64 * GST];
  __shared__ bf16_t sB[64 * GST];
  const int m0 = blockIdx.x * 64, n0 = blockIdx.y * 64;
  const int tid = threadIdx.x;
  const int lane = tid & 63, w = tid >> 6;
  const int wr = (w >> 1) * 32, wc = (w & 1) * 32;
  const int l16 = lane & 15, lg = lane >> 4;

  f32x4 acc[2][2] = {};

  for (int k0 = 0; k0 < DMODEL; k0 += 64) {
    #pragma unroll
    for (int i = 0; i < 2; ++i) {
      int chunk = tid + i * 256;
      int row = chunk >> 3, c8 = (chunk & 7) * 8;
      *reinterpret_cast<bf16x8*>(&sA[row * GST + c8]) =
          *reinterpret_cast<const bf16x8*>(&A[(size_t)(m0 + row) * DMODEL + k0 + c8]);
      *reinterpret_cast<bf16x8*>(&sB[row * GST + c8]) =
          *reinterpret_cast<const bf16x8*>(&Bt[(size_t)(n0 + row) * DMODEL + k0 + c8]);
    }
    __syncthreads();
    #pragma unroll
    for (int ks = 0; ks < 2; ++ks) {
      bf16x8 af[2], bfr[2];
      #pragma unroll
      for (int i = 0; i < 2; ++i)
        af[i] = *reinterpret_cast<const bf16x8*>(&sA[(wr + i * 16 + l16) * GST + ks * 32 + lg * 8]);
      #pragma unroll
      for (int j = 0; j < 2; ++j)
        bfr[j] = *reinterpret_cast<const bf16x8*>(&sB[(wc + j * 16 + l16) * GST + ks * 32 + lg * 8]);
      #pragma unroll
      for (int i = 0; i < 2; ++i)
        #pragma unroll
        for (int j = 0; j < 2; ++j)
          acc[i][j] = __builtin_amdgcn_mfma_f32_16x16x32_bf16(af[i], bfr[j], acc[i][j], 0, 0, 0);
    }
    __syncthreads();
  }

  #pragma unroll
  for (int i = 0; i < 2; ++i)
    #pragma unroll
    for (int j = 0; j < 2; ++j)
      #pragma unroll
      for (int r = 0; r < 4; ++r) {
        int m = m0 + wr + i * 16 + lg * 4 + r;
        int n = n0 + wc + j * 16 + l16;
        Cf[(size_t)m * DMODEL + n] = acc[i][j][r];
      }
}

// ---------- attention helpers ----------
__device__ __forceinline__ float redmax16(float v) {
  v = fmaxf(v, __shfl_xor(v, 1));
  v = fmaxf(v, __shfl_xor(v, 2));
  v = fmaxf(v, __shfl_xor(v, 4));
  v = fmaxf(v, __shfl_xor(v, 8));
  return v;
}
__device__ __forceinline__ float redsum16(float v) {
  v += __shfl_xor(v, 1);
  v += __shfl_xor(v, 2);
  v += __shfl_xor(v, 4);
  v += __shfl_xor(v, 8);
  return v;
}

// ---------- flash attention (R16 structure + per-offset bias LUT) ----------
#define SPS 68    // sP row stride (bf16) and sAcc row stride (f32)
#define SVS 136   // sV row stride (bf16)
#define DLUT 435  // bias-by-offset table: d in [-217, 217]

__global__ __launch_bounds__(512, 4) void attn_kernel(const bf16_t* __restrict__ Qh,
                                                      const bf16_t* __restrict__ Ql,
                                                      const bf16_t* __restrict__ Kh,
                                                      const bf16_t* __restrict__ Vt,
                                                      const float* __restrict__ relb,
                                                      bf16_t* __restrict__ ctx) {
  __shared__ bf16_t sKh[128 * 72];        // 18432 B
  __shared__ bf16_t sV [64 * SVS];        // 17408 B
  __shared__ bf16_t sP [2][64 * SPS];     // 17408 B (aliased as f32 sAcc in merge)
  __shared__ float sM[2][64], sL[2][64];  // 1024 B
  __shared__ float sBiasD[DLUT];          // 1740 B: bias(d) in log2 units
  float* sAcc = (float*)&sP[0][0];

  // XCD swizzle: 512 blocks = 8 XCDs x 64 contiguous q-tiles.
  const int id = blockIdx.x;
  const int lin = (id & 7) * 64 + (id >> 3);
  const int qt = lin & 31, h = (lin >> 5) & 7, b = lin >> 8;

  const int tid = threadIdx.x, lane = tid & 63, w = tid >> 6;
  const int l16 = lane & 15, lg = lane >> 4;
  const int q0 = qt * 64;
  const int qg = w & 3, half = w >> 2;
  const int wq = qg * 16;          // wave-owned q rows [wq, wq+16)
  const int kh0 = half * 64;       // wave-owned key half within the 128-key tile

  // build per-offset bias LUT (d = idx-217); covered by the init barrier below
  for (int i = tid; i < DLUT; i += 512) {
    int d = i - 217;
    int n = d < 0 ? -d : d;
    int bk = t5_bucket_abs(n) + (d < 0 ? 16 : 0);
    sBiasD[i] = relb[bk * NH + h] * LOG2E;
  }

  bf16x8 qh[2], ql[2];
  #pragma unroll
  for (int ks = 0; ks < 2; ++ks) {
    size_t o = (size_t)(b * QLEN + q0 + wq + l16) * INNER + h * DKV + ks * 32 + lg * 8;
    qh[ks] = *reinterpret_cast<const bf16x8*>(&Qh[o]);
    ql[ks] = *reinterpret_cast<const bf16x8*>(&Ql[o]);
  }

  f32x4 acc[4] = {};
  float mrow[4], lpart[4];
  #pragma unroll
  for (int r = 0; r < 4; ++r) { mrow[r] = -INFINITY; lpart[r] = 0.f; }

  // hoisted per-thread staging addresses (advance by constants per iter)
  const int krow = tid >> 3, kc8 = (tid & 7) * 8;      // K: 128 rows x 64 cols
  const int vrow = tid >> 4, vc8 = (tid & 15) * 8;     // V: 64 rows x 128 cols
  const bf16_t* kPtr = Kh + (size_t)(b * QLEN + krow) * INNER + h * DKV + kc8;
  const bf16_t* vPtr = Vt + (size_t)((b * NH + h) * DKV + vrow) * QLEN + vc8;
  const size_t kStep = (size_t)64 * INNER;
  bf16_t* kDst0 = &sKh[krow * 72 + kc8];
  bf16_t* kDst1 = &sKh[(krow + 64) * 72 + kc8];
  bf16_t* vDst0 = &sV[vrow * SVS + vc8];
  bf16_t* vDst1 = &sV[(vrow + 32) * SVS + vc8];

  bf16x8 rk0, rk1, rv0, rv1;
  rk0 = *reinterpret_cast<const bf16x8*>(kPtr);
  rk1 = *reinterpret_cast<const bf16x8*>(kPtr + kStep);
  rv0 = *reinterpret_cast<const bf16x8*>(vPtr);
  rv1 = *reinterpret_cast<const bf16x8*>(vPtr + (size_t)32 * QLEN);
  *reinterpret_cast<bf16x8*>(kDst0) = rk0;
  *reinterpret_cast<bf16x8*>(kDst1) = rk1;
  *reinterpret_cast<bf16x8*>(vDst0) = rv0;
  *reinterpret_cast<bf16x8*>(vDst1) = rv1;
  __syncthreads();

  const int NT = QLEN / 128;   // 16
  for (int kt = 0; kt < NT; ++kt) {
    const int k0 = kt * 128;
    const bool pf = (kt + 1 < NT);
    if (pf) {
      const bf16_t* kp = kPtr + (size_t)(k0 + 128) * INNER;
      const bf16_t* vp = vPtr + k0 + 128;
      rk0 = *reinterpret_cast<const bf16x8*>(kp);
      rk1 = *reinterpret_cast<const bf16x8*>(kp + kStep);
      rv0 = *reinterpret_cast<const bf16x8*>(vp);
      rv1 = *reinterpret_cast<const bf16x8*>(vp + (size_t)32 * QLEN);
    }

    // S = Q K^T over this wave's 64 keys, 2 passes (qh*kh + ql*kh)
    f32x4 s[4] = {};
    __builtin_amdgcn_s_setprio(1);
    #pragma unroll
    for (int ks = 0; ks < 2; ++ks) {
      bf16x8 kf[4];
      #pragma unroll
      for (int ni = 0; ni < 4; ++ni)
        kf[ni] = *reinterpret_cast<const bf16x8*>(
            &sKh[(kh0 + ni * 16 + l16) * 72 + ks * 32 + lg * 8]);
      #pragma unroll
      for (int ni = 0; ni < 4; ++ni) {
        s[ni] = __builtin_amdgcn_mfma_f32_16x16x32_bf16(qh[ks], kf[ni], s[ni], 0, 0, 0);
        s[ni] = __builtin_amdgcn_mfma_f32_16x16x32_bf16(ql[ks], kf[ni], s[ni], 0, 0, 0);
      }
    }
    __builtin_amdgcn_s_setprio(0);

    // bias: wave's key span is [kbase, kbase+64)
    const int kbase = k0 + kh0;
    const int dmin = q0 - (kbase + 63);
    const int dmax = q0 + 63 - kbase;
    const bool farP = dmin >= 91, farN = dmax <= -91;
    float fbias = 0.f;
    if (farP) fbias = sBiasD[217 + 91];
    else if (farN) fbias = sBiasD[217 - 91];
    else {
      #pragma unroll
      for (int ni = 0; ni < 4; ++ni) {
        int base = q0 + wq + 217 - (kbase + ni * 16 + l16);
        #pragma unroll
        for (int r = 0; r < 4; ++r)
          s[ni][r] += sBiasD[base + lg * 4 + r];
      }
    }

    // defer-max online softmax: cheap wave-vote, rare rescale
    float c[4], tmx[4];
    #pragma unroll
    for (int r = 0; r < 4; ++r) {
      tmx[r] = fmaxf(fmaxf(s[0][r], s[1][r]), fmaxf(s[2][r], s[3][r]));
      c[r] = mrow[r] - fbias;
    }
    float u = fmaxf(fmaxf(tmx[0] - c[0], tmx[1] - c[1]), fmaxf(tmx[2] - c[2], tmx[3] - c[3]));
    if (__any(u > THR_LOG2)) {
      #pragma unroll
      for (int r = 0; r < 4; ++r) {
        float rm = redmax16(tmx[r]) + fbias;
        float mnew = fmaxf(mrow[r], rm);
        float alpha = exp2f(mrow[r] - mnew);
        mrow[r] = mnew;
        c[r] = mnew - fbias;
        lpart[r] *= alpha;
        #pragma unroll
        for (int di = 0; di < 4; ++di) acc[di][r] *= alpha;
      }
    }

    // P = exp2(s - c); lane-local l partials; P -> LDS (wave-private 16x64 block)
    #pragma unroll
    for (int r = 0; r < 4; ++r) {
      float ps = 0.f;
      #pragma unroll
      for (int ni = 0; ni < 4; ++ni) {
        float p = exp2f(s[ni][r] - c[r]);
        ps += p;
        sP[half][(wq + lg * 4 + r) * SPS + ni * 16 + l16] = (bf16_t)p;
      }
      lpart[r] += ps;
    }

    // acc += P * V  (this wave's 64 keys)
    __builtin_amdgcn_s_setprio(1);
    #pragma unroll
    for (int ks = 0; ks < 2; ++ks) {
      bf16x8 pfr, vf[4];
      pfr = *reinterpret_cast<const bf16x8*>(&sP[half][(wq + l16) * SPS + ks * 32 + lg * 8]);
      #pragma unroll
      for (int di = 0; di < 4; ++di)
        vf[di] = *reinterpret_cast<const bf16x8*>(
            &sV[(di * 16 + l16) * SVS + kh0 + ks * 32 + lg * 8]);
      #pragma unroll
      for (int di = 0; di < 4; ++di)
        acc[di] = __builtin_amdgcn_mfma_f32_16x16x32_bf16(pfr, vf[di], acc[di], 0, 0, 0);
    }
    __builtin_amdgcn_s_setprio(0);

    __syncthreads();                 // all waves done reading this tile
    if (pf) {
      *reinterpret_cast<bf16x8*>(kDst0) = rk0;
      *reinterpret_cast<bf16x8*>(kDst1) = rk1;
      *reinterpret_cast<bf16x8*>(vDst0) = rv0;
      *reinterpret_cast<bf16x8*>(vDst1) = rv1;
    }
    __syncthreads();                 // next tile visible
  }

  // ----- merge the two key-halves (LSE combine) -----
  float lrow[4];
  #pragma unroll
  for (int r = 0; r < 4; ++r) lrow[r] = redsum16(lpart[r]);

  if (l16 == 0) {
    #pragma unroll
    for (int r = 0; r < 4; ++r) {
      int row = wq + lg * 4 + r;
      sM[half][row] = mrow[r];
      sL[half][row] = lrow[r];
    }
  }
  __syncthreads();

  float eh[4], denom[4];
  #pragma unroll
  for (int r = 0; r < 4; ++r) {
    int row = wq + lg * 4 + r;
    float m0 = sM[0][row], m1 = sM[1][row];
    float l0 = sL[0][row], l1 = sL[1][row];
    float M = fmaxf(m0, m1);
    float e0 = exp2f(m0 - M), e1 = exp2f(m1 - M);
    denom[r] = l0 * e0 + l1 * e1;
    eh[r] = half ? e1 : e0;
  }

  if (half == 1) {    // sAcc aliases sP: all sP reads completed before last barrier
    #pragma unroll
    for (int di = 0; di < 4; ++di)
      #pragma unroll
      for (int r = 0; r < 4; ++r)
        sAcc[(wq + lg * 4 + r) * SPS + di * 16 + l16] = acc[di][r] * eh[r];
  }
  __syncthreads();

  if (half == 0) {
    #pragma unroll
    for (int di = 0; di < 4; ++di)
      #pragma unroll
      for (int r = 0; r < 4; ++r) {
        int row = wq + lg * 4 + r;
        float v = (acc[di][r] * eh[r] + sAcc[row * SPS + di * 16 + l16]) / denom[r];
        ctx[(size_t)(b * QLEN + q0 + row) * INNER + h * DKV + di * 16 + l16] = (bf16_t)v;
      }
  }
}

extern "C" void kernel_launch(void* const* d_in, const int* in_sizes, int n_in,
                              void* d_out, int out_size, void* d_ws, size_t ws_size,
                              hipStream_t stream) {
  const float* X    = (const float*)d_in[0];
  const float* Wq   = (const float*)d_in[1];
  const float* Wk   = (const float*)d_in[2];
  const float* Wv   = (const float*)d_in[3];
  const float* Wo   = (const float*)d_in[4];
  const float* relb = (const float*)d_in[5];
  float* out = (float*)d_out;

  const size_t WSZ = 262144, XSZ = 2097152;
  bf16_t* ws   = (bf16_t*)d_ws;
  bf16_t* Wq_h = ws;              bf16_t* Wq_l = Wq_h + WSZ;
  bf16_t* Wk_h = Wq_l + WSZ;      bf16_t* Wk_l = Wk_h + WSZ;
  bf16_t* Wv_h = Wk_l + WSZ;      bf16_t* Wv_l = Wv_h + WSZ;
  bf16_t* Wo_h = Wv_l + WSZ;      bf16_t* Wo_l = Wo_h + WSZ;
  bf16_t* buf0 = Wo_l + WSZ;      bf16_t* buf1 = buf0 + XSZ;
  bf16_t* Q_h  = buf1 + XSZ;      bf16_t* Q_l  = Q_h + XSZ;
  bf16_t* K_h  = Q_l + XSZ;
  bf16_t* Vt   = buf1;            // V^T [b][h*64+d][s]
  bf16_t* ctx  = buf0;            // attention output

  transpose512_split_all<<<dim3(16, 16, 4), dim3(32, 8), 0, stream>>>(
      Wq, Wk, Wv, Wo, Wq_h, Wq_l, Wk_h, Wk_l, Wv_h, Wv_l, Wo_h, Wo_l);

  gemm_qkv<<<dim3(64, 24), 256, 0, stream>>>(X, Wq_h, Wq_l, Wk_h, Wk_l, Wv_h,
                                             Q_h, Q_l, K_h, Vt);

  attn_kernel<<<dim3(512), 512, 0, stream>>>(Q_h, Q_l, K_h, Vt, relb, ctx);

  gemm_out<<<dim3(64, 8), 256, 0, stream>>>(ctx, Wo_h, out);
}

// Round 19
// 99.912 us; speedup vs baseline: 1.1873x; 1.0363x over previous
//
#include <hip/hip_runtime.h>
#include <hip/hip_bf16.h>
#include <cmath>

typedef __bf16 bf16_t;
typedef __bf16 bf16x8 __attribute__((ext_vector_type(8)));
typedef __bf16 bf16x4 __attribute__((ext_vector_type(4)));
typedef float f32x4 __attribute__((ext_vector_type(4)));

#define QLEN 2048
#define DMODEL 512
#define NH 8
#define DKV 64
#define INNER 512
#define LOG2E 1.44269504f
#define THR_LOG2 11.5415603f   // 8 * log2(e)

// ---------- prep: 4 weight transposes fused: Wt[n][k] = W[k][n], hi/lo split ----------
__global__ __launch_bounds__(256) void transpose512_split_all(
    const float* __restrict__ W0, const float* __restrict__ W1,
    const float* __restrict__ W2, const float* __restrict__ W3,
    bf16_t* __restrict__ H0, bf16_t* __restrict__ L0,
    bf16_t* __restrict__ H1, bf16_t* __restrict__ L1,
    bf16_t* __restrict__ H2, bf16_t* __restrict__ L2,
    bf16_t* __restrict__ H3, bf16_t* __restrict__ L3) {
  __shared__ float tile[32][33];
  int z = blockIdx.z;
  const float* W = z == 0 ? W0 : z == 1 ? W1 : z == 2 ? W2 : W3;
  bf16_t* Whi    = z == 0 ? H0 : z == 1 ? H1 : z == 2 ? H2 : H3;
  bf16_t* Wlo    = z == 0 ? L0 : z == 1 ? L1 : z == 2 ? L2 : L3;
  int bk = blockIdx.x * 32, bn = blockIdx.y * 32;
  int tx = threadIdx.x, ty = threadIdx.y;
  #pragma unroll
  for (int i = 0; i < 32; i += 8)
    tile[ty + i][tx] = W[(size_t)(bk + ty + i) * DMODEL + bn + tx];
  __syncthreads();
  #pragma unroll
  for (int i = 0; i < 32; i += 8) {
    float v = tile[tx][ty + i];
    bf16_t hb = (bf16_t)v;
    size_t o = (size_t)(bn + ty + i) * DMODEL + bk + tx;
    Whi[o] = hb;
    Wlo[o] = (bf16_t)(v - (float)hb);
  }
}

// ---------- helpers ----------
__device__ __forceinline__ void splitx8(const float4& v0, const float4& v1,
                                        bf16x8& h, bf16x8& l) {
  #pragma unroll
  for (int j = 0; j < 4; ++j) {
    float x = (&v0.x)[j];
    bf16_t hb = (bf16_t)x;
    h[j] = hb; l[j] = (bf16_t)(x - (float)hb);
  }
  #pragma unroll
  for (int j = 0; j < 4; ++j) {
    float x = (&v1.x)[j];
    bf16_t hb = (bf16_t)x;
    h[4 + j] = hb; l[4 + j] = (bf16_t)(x - (float)hb);
  }
}
__device__ __forceinline__ bf16x8 castx8(const float4& v0, const float4& v1) {
  bf16x8 h;
  #pragma unroll
  for (int j = 0; j < 4; ++j) h[j] = (bf16_t)(&v0.x)[j];
  #pragma unroll
  for (int j = 0; j < 4; ++j) h[4 + j] = (bf16_t)(&v1.x)[j];
  return h;
}

__device__ __forceinline__ int t5_bucket_abs(int n) {
  if (n < 8)  return n;
  if (n < 12) return 8;
  if (n < 16) return 9;
  if (n < 23) return 10;
  if (n < 32) return 11;
  if (n < 46) return 12;
  if (n < 64) return 13;
  if (n < 91) return 14;
  return 15;
}

#define GST 72

// ---------- single-pass bf16 GEMM, BM=BN=64 ----------
// AF32: A read as f32 and cast-hi during staging (V projection).
// MODE 1: bf16 transposed (V): C[(b*512+n)*2048+s]; MODE 2: f32 natural.
template<int MODE, int AF32>
__global__ __launch_bounds__(256) void gemm64(const bf16_t* __restrict__ Ab,
                                              const float* __restrict__ Af,
                                              const bf16_t* __restrict__ Bt,
                                              bf16_t* __restrict__ Cb,
                                              float* __restrict__ Cf) {
  __shared__ bf16_t sA[64 * GST];
  __shared__ bf16_t sB[64 * GST];
  const int m0 = blockIdx.x * 64, n0 = blockIdx.y * 64;
  const int tid = threadIdx.x;
  const int lane = tid & 63, w = tid >> 6;
  const int wr = (w >> 1) * 32, wc = (w & 1) * 32;
  const int l16 = lane & 15, lg = lane >> 4;

  f32x4 acc[2][2] = {};

  for (int k0 = 0; k0 < DMODEL; k0 += 64) {
    #pragma unroll
    for (int i = 0; i < 2; ++i) {
      int chunk = tid + i * 256;
      int row = chunk >> 3, c8 = (chunk & 7) * 8;
      if (AF32) {
        const float4* src = reinterpret_cast<const float4*>(
            &Af[(size_t)(m0 + row) * DMODEL + k0 + c8]);
        *reinterpret_cast<bf16x8*>(&sA[row * GST + c8]) = castx8(src[0], src[1]);
      } else {
        *reinterpret_cast<bf16x8*>(&sA[row * GST + c8]) =
            *reinterpret_cast<const bf16x8*>(&Ab[(size_t)(m0 + row) * DMODEL + k0 + c8]);
      }
      *reinterpret_cast<bf16x8*>(&sB[row * GST + c8]) =
          *reinterpret_cast<const bf16x8*>(&Bt[(size_t)(n0 + row) * DMODEL + k0 + c8]);
    }
    __syncthreads();
    #pragma unroll
    for (int ks = 0; ks < 2; ++ks) {
      bf16x8 af[2], bfr[2];
      #pragma unroll
      for (int i = 0; i < 2; ++i)
        af[i] = *reinterpret_cast<const bf16x8*>(&sA[(wr + i * 16 + l16) * GST + ks * 32 + lg * 8]);
      #pragma unroll
      for (int j = 0; j < 2; ++j)
        bfr[j] = *reinterpret_cast<const bf16x8*>(&sB[(wc + j * 16 + l16) * GST + ks * 32 + lg * 8]);
      #pragma unroll
      for (int i = 0; i < 2; ++i)
        #pragma unroll
        for (int j = 0; j < 2; ++j)
          acc[i][j] = __builtin_amdgcn_mfma_f32_16x16x32_bf16(af[i], bfr[j], acc[i][j], 0, 0, 0);
    }
    __syncthreads();
  }

  #pragma unroll
  for (int i = 0; i < 2; ++i)
    #pragma unroll
    for (int j = 0; j < 2; ++j)
      #pragma unroll
      for (int r = 0; r < 4; ++r) {
        int m = m0 + wr + i * 16 + lg * 4 + r;
        int n = n0 + wc + j * 16 + l16;
        float v = acc[i][j][r];
        if (MODE == 1) {
          int b = m >> 11, s = m & (QLEN - 1);
          Cb[(size_t)(b * INNER + n) * QLEN + s] = (bf16_t)v;
        } else {
          Cf[(size_t)m * DMODEL + n] = v;
        }
      }
}

// ---------- fused Q+K 3-pass split GEMM: BM=64, BN=64, grid (64,16) ----------
// y<8: Q (n0=y*64, *log2e, hi/lo out); y>=8: K (hi out). LDS 36.9KB -> 4 blocks/CU.
__global__ __launch_bounds__(256) void gemm_qk_split(const float* __restrict__ X,
                                                     const bf16_t* __restrict__ Bqh,
                                                     const bf16_t* __restrict__ Bql,
                                                     const bf16_t* __restrict__ Bkh,
                                                     const bf16_t* __restrict__ Bkl,
                                                     bf16_t* __restrict__ Qh,
                                                     bf16_t* __restrict__ Ql,
                                                     bf16_t* __restrict__ Kh) {
  __shared__ bf16_t sAh[64 * GST];
  __shared__ bf16_t sAl[64 * GST];
  __shared__ bf16_t sBh[64 * GST];
  __shared__ bf16_t sBl[64 * GST];
  const int m0 = blockIdx.x * 64;
  const int y = blockIdx.y;
  const bool isK = y >= 8;
  const int n0 = (y & 7) * 64;
  const bf16_t* __restrict__ Bh = isK ? Bkh : Bqh;
  const bf16_t* __restrict__ Bl = isK ? Bkl : Bql;

  const int tid = threadIdx.x;
  const int lane = tid & 63, w = tid >> 6;
  const int wr = (w >> 1) * 32, wc = (w & 1) * 32;
  const int l16 = lane & 15, lg = lane >> 4;

  f32x4 acc[2][2] = {};

  for (int k0 = 0; k0 < DMODEL; k0 += 64) {
    #pragma unroll
    for (int i = 0; i < 2; ++i) {
      int chunk = tid + i * 256;
      int row = chunk >> 3, c8 = (chunk & 7) * 8;
      const float4* src = reinterpret_cast<const float4*>(
          &X[(size_t)(m0 + row) * DMODEL + k0 + c8]);
      bf16x8 h, l;
      splitx8(src[0], src[1], h, l);
      *reinterpret_cast<bf16x8*>(&sAh[row * GST + c8]) = h;
      *reinterpret_cast<bf16x8*>(&sAl[row * GST + c8]) = l;
      size_t gb = (size_t)(n0 + row) * DMODEL + k0 + c8;
      *reinterpret_cast<bf16x8*>(&sBh[row * GST + c8]) = *reinterpret_cast<const bf16x8*>(&Bh[gb]);
      *reinterpret_cast<bf16x8*>(&sBl[row * GST + c8]) = *reinterpret_cast<const bf16x8*>(&Bl[gb]);
    }
    __syncthreads();
    #pragma unroll
    for (int ks = 0; ks < 2; ++ks) {
      bf16x8 ah[2], al[2], bh[2], bl[2];
      #pragma unroll
      for (int i = 0; i < 2; ++i) {
        int ro = (wr + i * 16 + l16) * GST + ks * 32 + lg * 8;
        ah[i] = *reinterpret_cast<const bf16x8*>(&sAh[ro]);
        al[i] = *reinterpret_cast<const bf16x8*>(&sAl[ro]);
      }
      #pragma unroll
      for (int j = 0; j < 2; ++j) {
        int ro = (wc + j * 16 + l16) * GST + ks * 32 + lg * 8;
        bh[j] = *reinterpret_cast<const bf16x8*>(&sBh[ro]);
        bl[j] = *reinterpret_cast<const bf16x8*>(&sBl[ro]);
      }
      #pragma unroll
      for (int i = 0; i < 2; ++i)
        #pragma unroll
        for (int j = 0; j < 2; ++j) {
          acc[i][j] = __builtin_amdgcn_mfma_f32_16x16x32_bf16(ah[i], bh[j], acc[i][j], 0, 0, 0);
          acc[i][j] = __builtin_amdgcn_mfma_f32_16x16x32_bf16(ah[i], bl[j], acc[i][j], 0, 0, 0);
          acc[i][j] = __builtin_amdgcn_mfma_f32_16x16x32_bf16(al[i], bh[j], acc[i][j], 0, 0, 0);
        }
    }
    __syncthreads();
  }

  #pragma unroll
  for (int i = 0; i < 2; ++i)
    #pragma unroll
    for (int j = 0; j < 2; ++j)
      #pragma unroll
      for (int r = 0; r < 4; ++r) {
        int m = m0 + wr + i * 16 + lg * 4 + r;
        int n = n0 + wc + j * 16 + l16;
        float v = acc[i][j][r];
        if (!isK) {
          v *= LOG2E;
          bf16_t hb = (bf16_t)v;
          size_t o = (size_t)m * INNER + n;
          Qh[o] = hb;
          Ql[o] = (bf16_t)(v - (float)hb);
        } else {
          Kh[(size_t)m * INNER + n] = (bf16_t)v;
        }
      }
}

// ---------- attention helpers ----------
__device__ __forceinline__ float redmax16(float v) {
  v = fmaxf(v, __shfl_xor(v, 1));
  v = fmaxf(v, __shfl_xor(v, 2));
  v = fmaxf(v, __shfl_xor(v, 4));
  v = fmaxf(v, __shfl_xor(v, 8));
  return v;
}
__device__ __forceinline__ float redsum16(float v) {
  v += __shfl_xor(v, 1);
  v += __shfl_xor(v, 2);
  v += __shfl_xor(v, 4);
  v += __shfl_xor(v, 8);
  return v;
}

// ---------- flash attention (R17-exact: bias LUT + hoisted staging) ----------
#define SPS 68    // sP row stride (bf16) and sAcc row stride (f32)
#define SVS 136   // sV row stride (bf16)
#define DLUT 435  // bias-by-offset table: d in [-217, 217]

__global__ __launch_bounds__(512, 4) void attn_kernel(const bf16_t* __restrict__ Qh,
                                                      const bf16_t* __restrict__ Ql,
                                                      const bf16_t* __restrict__ Kh,
                                                      const bf16_t* __restrict__ Vt,
                                                      const float* __restrict__ relb,
                                                      bf16_t* __restrict__ ctx) {
  __shared__ bf16_t sKh[128 * 72];        // 18432 B
  __shared__ bf16_t sV [64 * SVS];        // 17408 B
  __shared__ bf16_t sP [2][64 * SPS];     // 17408 B (aliased as f32 sAcc in merge)
  __shared__ float sM[2][64], sL[2][64];  // 1024 B
  __shared__ float sBiasD[DLUT];          // 1740 B: bias(d) in log2 units
  float* sAcc = (float*)&sP[0][0];

  // XCD swizzle: 512 blocks = 8 XCDs x 64 contiguous q-tiles.
  const int id = blockIdx.x;
  const int lin = (id & 7) * 64 + (id >> 3);
  const int qt = lin & 31, h = (lin >> 5) & 7, b = lin >> 8;

  const int tid = threadIdx.x, lane = tid & 63, w = tid >> 6;
  const int l16 = lane & 15, lg = lane >> 4;
  const int q0 = qt * 64;
  const int qg = w & 3, half = w >> 2;
  const int wq = qg * 16;          // wave-owned q rows [wq, wq+16)
  const int kh0 = half * 64;       // wave-owned key half within the 128-key tile

  // build per-offset bias LUT (d = idx-217); covered by the init barrier below
  for (int i = tid; i < DLUT; i += 512) {
    int d = i - 217;
    int n = d < 0 ? -d : d;
    int bk = t5_bucket_abs(n) + (d < 0 ? 16 : 0);
    sBiasD[i] = relb[bk * NH + h] * LOG2E;
  }

  bf16x8 qh[2], ql[2];
  #pragma unroll
  for (int ks = 0; ks < 2; ++ks) {
    size_t o = (size_t)(b * QLEN + q0 + wq + l16) * INNER + h * DKV + ks * 32 + lg * 8;
    qh[ks] = *reinterpret_cast<const bf16x8*>(&Qh[o]);
    ql[ks] = *reinterpret_cast<const bf16x8*>(&Ql[o]);
  }

  f32x4 acc[4] = {};
  float mrow[4], lpart[4];
  #pragma unroll
  for (int r = 0; r < 4; ++r) { mrow[r] = -INFINITY; lpart[r] = 0.f; }

  // hoisted per-thread staging addresses (advance by constants per iter)
  const int krow = tid >> 3, kc8 = (tid & 7) * 8;      // K: 128 rows x 64 cols
  const int vrow = tid >> 4, vc8 = (tid & 15) * 8;     // V: 64 rows x 128 cols
  const bf16_t* kPtr = Kh + (size_t)(b * QLEN + krow) * INNER + h * DKV + kc8;
  const bf16_t* vPtr = Vt + (size_t)((b * NH + h) * DKV + vrow) * QLEN + vc8;
  const size_t kStep = (size_t)64 * INNER;
  bf16_t* kDst0 = &sKh[krow * 72 + kc8];
  bf16_t* kDst1 = &sKh[(krow + 64) * 72 + kc8];
  bf16_t* vDst0 = &sV[vrow * SVS + vc8];
  bf16_t* vDst1 = &sV[(vrow + 32) * SVS + vc8];

  bf16x8 rk0, rk1, rv0, rv1;
  rk0 = *reinterpret_cast<const bf16x8*>(kPtr);
  rk1 = *reinterpret_cast<const bf16x8*>(kPtr + kStep);
  rv0 = *reinterpret_cast<const bf16x8*>(vPtr);
  rv1 = *reinterpret_cast<const bf16x8*>(vPtr + (size_t)32 * QLEN);
  *reinterpret_cast<bf16x8*>(kDst0) = rk0;
  *reinterpret_cast<bf16x8*>(kDst1) = rk1;
  *reinterpret_cast<bf16x8*>(vDst0) = rv0;
  *reinterpret_cast<bf16x8*>(vDst1) = rv1;
  __syncthreads();

  const int NT = QLEN / 128;   // 16
  for (int kt = 0; kt < NT; ++kt) {
    const int k0 = kt * 128;
    const bool pf = (kt + 1 < NT);
    if (pf) {
      const bf16_t* kp = kPtr + (size_t)(k0 + 128) * INNER;
      const bf16_t* vp = vPtr + k0 + 128;
      rk0 = *reinterpret_cast<const bf16x8*>(kp);
      rk1 = *reinterpret_cast<const bf16x8*>(kp + kStep);
      rv0 = *reinterpret_cast<const bf16x8*>(vp);
      rv1 = *reinterpret_cast<const bf16x8*>(vp + (size_t)32 * QLEN);
    }

    // S = Q K^T over this wave's 64 keys, 2 passes (qh*kh + ql*kh)
    f32x4 s[4] = {};
    __builtin_amdgcn_s_setprio(1);
    #pragma unroll
    for (int ks = 0; ks < 2; ++ks) {
      bf16x8 kf[4];
      #pragma unroll
      for (int ni = 0; ni < 4; ++ni)
        kf[ni] = *reinterpret_cast<const bf16x8*>(
            &sKh[(kh0 + ni * 16 + l16) * 72 + ks * 32 + lg * 8]);
      #pragma unroll
      for (int ni = 0; ni < 4; ++ni) {
        s[ni] = __builtin_amdgcn_mfma_f32_16x16x32_bf16(qh[ks], kf[ni], s[ni], 0, 0, 0);
        s[ni] = __builtin_amdgcn_mfma_f32_16x16x32_bf16(ql[ks], kf[ni], s[ni], 0, 0, 0);
      }
    }
    __builtin_amdgcn_s_setprio(0);

    // bias: wave's key span is [kbase, kbase+64)
    const int kbase = k0 + kh0;
    const int dmin = q0 - (kbase + 63);
    const int dmax = q0 + 63 - kbase;
    const bool farP = dmin >= 91, farN = dmax <= -91;
    float fbias = 0.f;
    if (farP) fbias = sBiasD[217 + 91];
    else if (farN) fbias = sBiasD[217 - 91];
    else {
      #pragma unroll
      for (int ni = 0; ni < 4; ++ni) {
        int base = q0 + wq + 217 - (kbase + ni * 16 + l16);
        #pragma unroll
        for (int r = 0; r < 4; ++r)
          s[ni][r] += sBiasD[base + lg * 4 + r];
      }
    }

    // defer-max online softmax: cheap wave-vote, rare rescale
    float c[4], tmx[4];
    #pragma unroll
    for (int r = 0; r < 4; ++r) {
      tmx[r] = fmaxf(fmaxf(s[0][r], s[1][r]), fmaxf(s[2][r], s[3][r]));
      c[r] = mrow[r] - fbias;
    }
    float u = fmaxf(fmaxf(tmx[0] - c[0], tmx[1] - c[1]), fmaxf(tmx[2] - c[2], tmx[3] - c[3]));
    if (__any(u > THR_LOG2)) {
      #pragma unroll
      for (int r = 0; r < 4; ++r) {
        float rm = redmax16(tmx[r]) + fbias;
        float mnew = fmaxf(mrow[r], rm);
        float alpha = exp2f(mrow[r] - mnew);
        mrow[r] = mnew;
        c[r] = mnew - fbias;
        lpart[r] *= alpha;
        #pragma unroll
        for (int di = 0; di < 4; ++di) acc[di][r] *= alpha;
      }
    }

    // P = exp2(s - c); lane-local l partials; P -> LDS (wave-private 16x64 block)
    #pragma unroll
    for (int r = 0; r < 4; ++r) {
      float ps = 0.f;
      #pragma unroll
      for (int ni = 0; ni < 4; ++ni) {
        float p = exp2f(s[ni][r] - c[r]);
        ps += p;
        sP[half][(wq + lg * 4 + r) * SPS + ni * 16 + l16] = (bf16_t)p;
      }
      lpart[r] += ps;
    }

    // acc += P * V  (this wave's 64 keys)
    __builtin_amdgcn_s_setprio(1);
    #pragma unroll
    for (int ks = 0; ks < 2; ++ks) {
      bf16x8 pfr, vf[4];
      pfr = *reinterpret_cast<const bf16x8*>(&sP[half][(wq + l16) * SPS + ks * 32 + lg * 8]);
      #pragma unroll
      for (int di = 0; di < 4; ++di)
        vf[di] = *reinterpret_cast<const bf16x8*>(
            &sV[(di * 16 + l16) * SVS + kh0 + ks * 32 + lg * 8]);
      #pragma unroll
      for (int di = 0; di < 4; ++di)
        acc[di] = __builtin_amdgcn_mfma_f32_16x16x32_bf16(pfr, vf[di], acc[di], 0, 0, 0);
    }
    __builtin_amdgcn_s_setprio(0);

    __syncthreads();                 // all waves done reading this tile
    if (pf) {
      *reinterpret_cast<bf16x8*>(kDst0) = rk0;
      *reinterpret_cast<bf16x8*>(kDst1) = rk1;
      *reinterpret_cast<bf16x8*>(vDst0) = rv0;
      *reinterpret_cast<bf16x8*>(vDst1) = rv1;
    }
    __syncthreads();                 // next tile visible
  }

  // ----- merge the two key-halves (LSE combine) -----
  float lrow[4];
  #pragma unroll
  for (int r = 0; r < 4; ++r) lrow[r] = redsum16(lpart[r]);

  if (l16 == 0) {
    #pragma unroll
    for (int r = 0; r < 4; ++r) {
      int row = wq + lg * 4 + r;
      sM[half][row] = mrow[r];
      sL[half][row] = lrow[r];
    }
  }
  __syncthreads();

  float eh[4], denom[4];
  #pragma unroll
  for (int r = 0; r < 4; ++r) {
    int row = wq + lg * 4 + r;
    float m0 = sM[0][row], m1 = sM[1][row];
    float l0 = sL[0][row], l1 = sL[1][row];
    float M = fmaxf(m0, m1);
    float e0 = exp2f(m0 - M), e1 = exp2f(m1 - M);
    denom[r] = l0 * e0 + l1 * e1;
    eh[r] = half ? e1 : e0;
  }

  if (half == 1) {    // sAcc aliases sP: all sP reads completed before last barrier
    #pragma unroll
    for (int di = 0; di < 4; ++di)
      #pragma unroll
      for (int r = 0; r < 4; ++r)
        sAcc[(wq + lg * 4 + r) * SPS + di * 16 + l16] = acc[di][r] * eh[r];
  }
  __syncthreads();

  if (half == 0) {
    #pragma unroll
    for (int di = 0; di < 4; ++di)
      #pragma unroll
      for (int r = 0; r < 4; ++r) {
        int row = wq + lg * 4 + r;
        float v = (acc[di][r] * eh[r] + sAcc[row * SPS + di * 16 + l16]) / denom[r];
        ctx[(size_t)(b * QLEN + q0 + row) * INNER + h * DKV + di * 16 + l16] = (bf16_t)v;
      }
  }
}

extern "C" void kernel_launch(void* const* d_in, const int* in_sizes, int n_in,
                              void* d_out, int out_size, void* d_ws, size_t ws_size,
                              hipStream_t stream) {
  const float* X    = (const float*)d_in[0];
  const float* Wq   = (const float*)d_in[1];
  const float* Wk   = (const float*)d_in[2];
  const float* Wv   = (const float*)d_in[3];
  const float* Wo   = (const float*)d_in[4];
  const float* relb = (const float*)d_in[5];
  float* out = (float*)d_out;

  const size_t WSZ = 262144, XSZ = 2097152;
  bf16_t* ws   = (bf16_t*)d_ws;
  bf16_t* Wq_h = ws;              bf16_t* Wq_l = Wq_h + WSZ;
  bf16_t* Wk_h = Wq_l + WSZ;      bf16_t* Wk_l = Wk_h + WSZ;
  bf16_t* Wv_h = Wk_l + WSZ;      bf16_t* Wv_l = Wv_h + WSZ;
  bf16_t* Wo_h = Wv_l + WSZ;      bf16_t* Wo_l = Wo_h + WSZ;
  bf16_t* buf0 = Wo_l + WSZ;      bf16_t* buf1 = buf0 + XSZ;
  bf16_t* Q_h  = buf1 + XSZ;      bf16_t* Q_l  = Q_h + XSZ;
  bf16_t* K_h  = Q_l + XSZ;
  bf16_t* Vt   = buf1;            // V^T [b][h*64+d][s]
  bf16_t* ctx  = buf0;            // attention output

  transpose512_split_all<<<dim3(16, 16, 4), dim3(32, 8), 0, stream>>>(
      Wq, Wk, Wv, Wo, Wq_h, Wq_l, Wk_h, Wk_l, Wv_h, Wv_l, Wo_h, Wo_l);

  gemm_qk_split<<<dim3(64, 16), 256, 0, stream>>>(X, Wq_h, Wq_l, Wk_h, Wk_l,
                                                  Q_h, Q_l, K_h);
  gemm64<1, 1><<<dim3(64, 8), 256, 0, stream>>>(nullptr, X, Wv_h, Vt, nullptr);

  attn_kernel<<<dim3(512), 512, 0, stream>>>(Q_h, Q_l, K_h, Vt, relb, ctx);

  gemm64<2, 0><<<dim3(64, 8), 256, 0, stream>>>(ctx, nullptr, Wo_h, nullptr, out);
}

// Round 20
// 99.190 us; speedup vs baseline: 1.1960x; 1.0073x over previous
//
#include <hip/hip_runtime.h>
#include <hip/hip_bf16.h>
#include <cmath>

typedef __bf16 bf16_t;
typedef __bf16 bf16x8 __attribute__((ext_vector_type(8)));
typedef __bf16 bf16x4 __attribute__((ext_vector_type(4)));
typedef float f32x4 __attribute__((ext_vector_type(4)));

#define QLEN 2048
#define DMODEL 512
#define NH 8
#define DKV 64
#define INNER 512
#define LOG2E 1.44269504f
#define THR_LOG2 11.5415603f   // 8 * log2(e)

// ---------- prep: 4 weight transposes fused: Wt[n][k] = W[k][n], hi/lo split ----------
__global__ __launch_bounds__(256) void transpose512_split_all(
    const float* __restrict__ W0, const float* __restrict__ W1,
    const float* __restrict__ W2, const float* __restrict__ W3,
    bf16_t* __restrict__ H0, bf16_t* __restrict__ L0,
    bf16_t* __restrict__ H1, bf16_t* __restrict__ L1,
    bf16_t* __restrict__ H2, bf16_t* __restrict__ L2,
    bf16_t* __restrict__ H3, bf16_t* __restrict__ L3) {
  __shared__ float tile[32][33];
  int z = blockIdx.z;
  const float* W = z == 0 ? W0 : z == 1 ? W1 : z == 2 ? W2 : W3;
  bf16_t* Whi    = z == 0 ? H0 : z == 1 ? H1 : z == 2 ? H2 : H3;
  bf16_t* Wlo    = z == 0 ? L0 : z == 1 ? L1 : z == 2 ? L2 : L3;
  int bk = blockIdx.x * 32, bn = blockIdx.y * 32;
  int tx = threadIdx.x, ty = threadIdx.y;
  #pragma unroll
  for (int i = 0; i < 32; i += 8)
    tile[ty + i][tx] = W[(size_t)(bk + ty + i) * DMODEL + bn + tx];
  __syncthreads();
  #pragma unroll
  for (int i = 0; i < 32; i += 8) {
    float v = tile[tx][ty + i];
    bf16_t hb = (bf16_t)v;
    size_t o = (size_t)(bn + ty + i) * DMODEL + bk + tx;
    Whi[o] = hb;
    Wlo[o] = (bf16_t)(v - (float)hb);
  }
}

// ---------- helpers ----------
__device__ __forceinline__ void splitx8(const float4& v0, const float4& v1,
                                        bf16x8& h, bf16x8& l) {
  #pragma unroll
  for (int j = 0; j < 4; ++j) {
    float x = (&v0.x)[j];
    bf16_t hb = (bf16_t)x;
    h[j] = hb; l[j] = (bf16_t)(x - (float)hb);
  }
  #pragma unroll
  for (int j = 0; j < 4; ++j) {
    float x = (&v1.x)[j];
    bf16_t hb = (bf16_t)x;
    h[4 + j] = hb; l[4 + j] = (bf16_t)(x - (float)hb);
  }
}
__device__ __forceinline__ bf16x8 castx8(const float4& v0, const float4& v1) {
  bf16x8 h;
  #pragma unroll
  for (int j = 0; j < 4; ++j) h[j] = (bf16_t)(&v0.x)[j];
  #pragma unroll
  for (int j = 0; j < 4; ++j) h[4 + j] = (bf16_t)(&v1.x)[j];
  return h;
}

__device__ __forceinline__ int t5_bucket_abs(int n) {
  if (n < 8)  return n;
  if (n < 12) return 8;
  if (n < 16) return 9;
  if (n < 23) return 10;
  if (n < 32) return 11;
  if (n < 46) return 12;
  if (n < 64) return 13;
  if (n < 91) return 14;
  return 15;
}

#define GST 72

// ---------- single-pass bf16 GEMM, BM=BN=64 ----------
// AF32: A read as f32 and cast-hi during staging (V projection).
// MODE 1: bf16 transposed (V): C[(b*512+n)*2048+s]; MODE 2: f32 natural.
template<int MODE, int AF32>
__global__ __launch_bounds__(256) void gemm64(const bf16_t* __restrict__ Ab,
                                              const float* __restrict__ Af,
                                              const bf16_t* __restrict__ Bt,
                                              bf16_t* __restrict__ Cb,
                                              float* __restrict__ Cf) {
  __shared__ bf16_t sA[64 * GST];
  __shared__ bf16_t sB[64 * GST];
  const int m0 = blockIdx.x * 64, n0 = blockIdx.y * 64;
  const int tid = threadIdx.x;
  const int lane = tid & 63, w = tid >> 6;
  const int wr = (w >> 1) * 32, wc = (w & 1) * 32;
  const int l16 = lane & 15, lg = lane >> 4;

  f32x4 acc[2][2] = {};

  for (int k0 = 0; k0 < DMODEL; k0 += 64) {
    #pragma unroll
    for (int i = 0; i < 2; ++i) {
      int chunk = tid + i * 256;
      int row = chunk >> 3, c8 = (chunk & 7) * 8;
      if (AF32) {
        const float4* src = reinterpret_cast<const float4*>(
            &Af[(size_t)(m0 + row) * DMODEL + k0 + c8]);
        *reinterpret_cast<bf16x8*>(&sA[row * GST + c8]) = castx8(src[0], src[1]);
      } else {
        *reinterpret_cast<bf16x8*>(&sA[row * GST + c8]) =
            *reinterpret_cast<const bf16x8*>(&Ab[(size_t)(m0 + row) * DMODEL + k0 + c8]);
      }
      *reinterpret_cast<bf16x8*>(&sB[row * GST + c8]) =
          *reinterpret_cast<const bf16x8*>(&Bt[(size_t)(n0 + row) * DMODEL + k0 + c8]);
    }
    __syncthreads();
    #pragma unroll
    for (int ks = 0; ks < 2; ++ks) {
      bf16x8 af[2], bfr[2];
      #pragma unroll
      for (int i = 0; i < 2; ++i)
        af[i] = *reinterpret_cast<const bf16x8*>(&sA[(wr + i * 16 + l16) * GST + ks * 32 + lg * 8]);
      #pragma unroll
      for (int j = 0; j < 2; ++j)
        bfr[j] = *reinterpret_cast<const bf16x8*>(&sB[(wc + j * 16 + l16) * GST + ks * 32 + lg * 8]);
      #pragma unroll
      for (int i = 0; i < 2; ++i)
        #pragma unroll
        for (int j = 0; j < 2; ++j)
          acc[i][j] = __builtin_amdgcn_mfma_f32_16x16x32_bf16(af[i], bfr[j], acc[i][j], 0, 0, 0);
    }
    __syncthreads();
  }

  #pragma unroll
  for (int i = 0; i < 2; ++i)
    #pragma unroll
    for (int j = 0; j < 2; ++j)
      #pragma unroll
      for (int r = 0; r < 4; ++r) {
        int m = m0 + wr + i * 16 + lg * 4 + r;
        int n = n0 + wc + j * 16 + l16;
        float v = acc[i][j][r];
        if (MODE == 1) {
          int b = m >> 11, s = m & (QLEN - 1);
          Cb[(size_t)(b * INNER + n) * QLEN + s] = (bf16_t)v;
        } else {
          Cf[(size_t)m * DMODEL + n] = v;
        }
      }
}

// ---------- fused Q+K 3-pass split GEMM: BM=64, BN=64, grid (64,16) ----------
// y<8: Q (n0=y*64, *log2e, hi/lo out); y>=8: K (hi out). LDS 36.9KB -> 4 blocks/CU.
__global__ __launch_bounds__(256) void gemm_qk_split(const float* __restrict__ X,
                                                     const bf16_t* __restrict__ Bqh,
                                                     const bf16_t* __restrict__ Bql,
                                                     const bf16_t* __restrict__ Bkh,
                                                     const bf16_t* __restrict__ Bkl,
                                                     bf16_t* __restrict__ Qh,
                                                     bf16_t* __restrict__ Ql,
                                                     bf16_t* __restrict__ Kh) {
  __shared__ bf16_t sAh[64 * GST];
  __shared__ bf16_t sAl[64 * GST];
  __shared__ bf16_t sBh[64 * GST];
  __shared__ bf16_t sBl[64 * GST];
  const int m0 = blockIdx.x * 64;
  const int y = blockIdx.y;
  const bool isK = y >= 8;
  const int n0 = (y & 7) * 64;
  const bf16_t* __restrict__ Bh = isK ? Bkh : Bqh;
  const bf16_t* __restrict__ Bl = isK ? Bkl : Bql;

  const int tid = threadIdx.x;
  const int lane = tid & 63, w = tid >> 6;
  const int wr = (w >> 1) * 32, wc = (w & 1) * 32;
  const int l16 = lane & 15, lg = lane >> 4;

  f32x4 acc[2][2] = {};

  for (int k0 = 0; k0 < DMODEL; k0 += 64) {
    #pragma unroll
    for (int i = 0; i < 2; ++i) {
      int chunk = tid + i * 256;
      int row = chunk >> 3, c8 = (chunk & 7) * 8;
      const float4* src = reinterpret_cast<const float4*>(
          &X[(size_t)(m0 + row) * DMODEL + k0 + c8]);
      bf16x8 h, l;
      splitx8(src[0], src[1], h, l);
      *reinterpret_cast<bf16x8*>(&sAh[row * GST + c8]) = h;
      *reinterpret_cast<bf16x8*>(&sAl[row * GST + c8]) = l;
      size_t gb = (size_t)(n0 + row) * DMODEL + k0 + c8;
      *reinterpret_cast<bf16x8*>(&sBh[row * GST + c8]) = *reinterpret_cast<const bf16x8*>(&Bh[gb]);
      *reinterpret_cast<bf16x8*>(&sBl[row * GST + c8]) = *reinterpret_cast<const bf16x8*>(&Bl[gb]);
    }
    __syncthreads();
    #pragma unroll
    for (int ks = 0; ks < 2; ++ks) {
      bf16x8 ah[2], al[2], bh[2], bl[2];
      #pragma unroll
      for (int i = 0; i < 2; ++i) {
        int ro = (wr + i * 16 + l16) * GST + ks * 32 + lg * 8;
        ah[i] = *reinterpret_cast<const bf16x8*>(&sAh[ro]);
        al[i] = *reinterpret_cast<const bf16x8*>(&sAl[ro]);
      }
      #pragma unroll
      for (int j = 0; j < 2; ++j) {
        int ro = (wc + j * 16 + l16) * GST + ks * 32 + lg * 8;
        bh[j] = *reinterpret_cast<const bf16x8*>(&sBh[ro]);
        bl[j] = *reinterpret_cast<const bf16x8*>(&sBl[ro]);
      }
      #pragma unroll
      for (int i = 0; i < 2; ++i)
        #pragma unroll
        for (int j = 0; j < 2; ++j) {
          acc[i][j] = __builtin_amdgcn_mfma_f32_16x16x32_bf16(ah[i], bh[j], acc[i][j], 0, 0, 0);
          acc[i][j] = __builtin_amdgcn_mfma_f32_16x16x32_bf16(ah[i], bl[j], acc[i][j], 0, 0, 0);
          acc[i][j] = __builtin_amdgcn_mfma_f32_16x16x32_bf16(al[i], bh[j], acc[i][j], 0, 0, 0);
        }
    }
    __syncthreads();
  }

  #pragma unroll
  for (int i = 0; i < 2; ++i)
    #pragma unroll
    for (int j = 0; j < 2; ++j)
      #pragma unroll
      for (int r = 0; r < 4; ++r) {
        int m = m0 + wr + i * 16 + lg * 4 + r;
        int n = n0 + wc + j * 16 + l16;
        float v = acc[i][j][r];
        if (!isK) {
          v *= LOG2E;
          bf16_t hb = (bf16_t)v;
          size_t o = (size_t)m * INNER + n;
          Qh[o] = hb;
          Ql[o] = (bf16_t)(v - (float)hb);
        } else {
          Kh[(size_t)m * INNER + n] = (bf16_t)v;
        }
      }
}

// ---------- attention helpers ----------
__device__ __forceinline__ float redmax16(float v) {
  v = fmaxf(v, __shfl_xor(v, 1));
  v = fmaxf(v, __shfl_xor(v, 2));
  v = fmaxf(v, __shfl_xor(v, 4));
  v = fmaxf(v, __shfl_xor(v, 8));
  return v;
}
__device__ __forceinline__ float redsum16(float v) {
  v += __shfl_xor(v, 1);
  v += __shfl_xor(v, 2);
  v += __shfl_xor(v, 4);
  v += __shfl_xor(v, 8);
  return v;
}

// ---------- flash attention (R19 minus s_setprio: lockstep waves, m190 regime) ----------
#define SPS 68    // sP row stride (bf16) and sAcc row stride (f32)
#define SVS 136   // sV row stride (bf16)
#define DLUT 435  // bias-by-offset table: d in [-217, 217]

__global__ __launch_bounds__(512, 4) void attn_kernel(const bf16_t* __restrict__ Qh,
                                                      const bf16_t* __restrict__ Ql,
                                                      const bf16_t* __restrict__ Kh,
                                                      const bf16_t* __restrict__ Vt,
                                                      const float* __restrict__ relb,
                                                      bf16_t* __restrict__ ctx) {
  __shared__ bf16_t sKh[128 * 72];        // 18432 B
  __shared__ bf16_t sV [64 * SVS];        // 17408 B
  __shared__ bf16_t sP [2][64 * SPS];     // 17408 B (aliased as f32 sAcc in merge)
  __shared__ float sM[2][64], sL[2][64];  // 1024 B
  __shared__ float sBiasD[DLUT];          // 1740 B: bias(d) in log2 units
  float* sAcc = (float*)&sP[0][0];

  // XCD swizzle: 512 blocks = 8 XCDs x 64 contiguous q-tiles.
  const int id = blockIdx.x;
  const int lin = (id & 7) * 64 + (id >> 3);
  const int qt = lin & 31, h = (lin >> 5) & 7, b = lin >> 8;

  const int tid = threadIdx.x, lane = tid & 63, w = tid >> 6;
  const int l16 = lane & 15, lg = lane >> 4;
  const int q0 = qt * 64;
  const int qg = w & 3, half = w >> 2;
  const int wq = qg * 16;          // wave-owned q rows [wq, wq+16)
  const int kh0 = half * 64;       // wave-owned key half within the 128-key tile

  // build per-offset bias LUT (d = idx-217); covered by the init barrier below
  for (int i = tid; i < DLUT; i += 512) {
    int d = i - 217;
    int n = d < 0 ? -d : d;
    int bk = t5_bucket_abs(n) + (d < 0 ? 16 : 0);
    sBiasD[i] = relb[bk * NH + h] * LOG2E;
  }

  bf16x8 qh[2], ql[2];
  #pragma unroll
  for (int ks = 0; ks < 2; ++ks) {
    size_t o = (size_t)(b * QLEN + q0 + wq + l16) * INNER + h * DKV + ks * 32 + lg * 8;
    qh[ks] = *reinterpret_cast<const bf16x8*>(&Qh[o]);
    ql[ks] = *reinterpret_cast<const bf16x8*>(&Ql[o]);
  }

  f32x4 acc[4] = {};
  float mrow[4], lpart[4];
  #pragma unroll
  for (int r = 0; r < 4; ++r) { mrow[r] = -INFINITY; lpart[r] = 0.f; }

  // hoisted per-thread staging addresses (advance by constants per iter)
  const int krow = tid >> 3, kc8 = (tid & 7) * 8;      // K: 128 rows x 64 cols
  const int vrow = tid >> 4, vc8 = (tid & 15) * 8;     // V: 64 rows x 128 cols
  const bf16_t* kPtr = Kh + (size_t)(b * QLEN + krow) * INNER + h * DKV + kc8;
  const bf16_t* vPtr = Vt + (size_t)((b * NH + h) * DKV + vrow) * QLEN + vc8;
  const size_t kStep = (size_t)64 * INNER;
  bf16_t* kDst0 = &sKh[krow * 72 + kc8];
  bf16_t* kDst1 = &sKh[(krow + 64) * 72 + kc8];
  bf16_t* vDst0 = &sV[vrow * SVS + vc8];
  bf16_t* vDst1 = &sV[(vrow + 32) * SVS + vc8];

  bf16x8 rk0, rk1, rv0, rv1;
  rk0 = *reinterpret_cast<const bf16x8*>(kPtr);
  rk1 = *reinterpret_cast<const bf16x8*>(kPtr + kStep);
  rv0 = *reinterpret_cast<const bf16x8*>(vPtr);
  rv1 = *reinterpret_cast<const bf16x8*>(vPtr + (size_t)32 * QLEN);
  *reinterpret_cast<bf16x8*>(kDst0) = rk0;
  *reinterpret_cast<bf16x8*>(kDst1) = rk1;
  *reinterpret_cast<bf16x8*>(vDst0) = rv0;
  *reinterpret_cast<bf16x8*>(vDst1) = rv1;
  __syncthreads();

  const int NT = QLEN / 128;   // 16
  for (int kt = 0; kt < NT; ++kt) {
    const int k0 = kt * 128;
    const bool pf = (kt + 1 < NT);
    if (pf) {
      const bf16_t* kp = kPtr + (size_t)(k0 + 128) * INNER;
      const bf16_t* vp = vPtr + k0 + 128;
      rk0 = *reinterpret_cast<const bf16x8*>(kp);
      rk1 = *reinterpret_cast<const bf16x8*>(kp + kStep);
      rv0 = *reinterpret_cast<const bf16x8*>(vp);
      rv1 = *reinterpret_cast<const bf16x8*>(vp + (size_t)32 * QLEN);
    }

    // S = Q K^T over this wave's 64 keys, 2 passes (qh*kh + ql*kh)
    f32x4 s[4] = {};
    #pragma unroll
    for (int ks = 0; ks < 2; ++ks) {
      bf16x8 kf[4];
      #pragma unroll
      for (int ni = 0; ni < 4; ++ni)
        kf[ni] = *reinterpret_cast<const bf16x8*>(
            &sKh[(kh0 + ni * 16 + l16) * 72 + ks * 32 + lg * 8]);
      #pragma unroll
      for (int ni = 0; ni < 4; ++ni) {
        s[ni] = __builtin_amdgcn_mfma_f32_16x16x32_bf16(qh[ks], kf[ni], s[ni], 0, 0, 0);
        s[ni] = __builtin_amdgcn_mfma_f32_16x16x32_bf16(ql[ks], kf[ni], s[ni], 0, 0, 0);
      }
    }

    // bias: wave's key span is [kbase, kbase+64)
    const int kbase = k0 + kh0;
    const int dmin = q0 - (kbase + 63);
    const int dmax = q0 + 63 - kbase;
    const bool farP = dmin >= 91, farN = dmax <= -91;
    float fbias = 0.f;
    if (farP) fbias = sBiasD[217 + 91];
    else if (farN) fbias = sBiasD[217 - 91];
    else {
      #pragma unroll
      for (int ni = 0; ni < 4; ++ni) {
        int base = q0 + wq + 217 - (kbase + ni * 16 + l16);
        #pragma unroll
        for (int r = 0; r < 4; ++r)
          s[ni][r] += sBiasD[base + lg * 4 + r];
      }
    }

    // defer-max online softmax: cheap wave-vote, rare rescale
    float c[4], tmx[4];
    #pragma unroll
    for (int r = 0; r < 4; ++r) {
      tmx[r] = fmaxf(fmaxf(s[0][r], s[1][r]), fmaxf(s[2][r], s[3][r]));
      c[r] = mrow[r] - fbias;
    }
    float u = fmaxf(fmaxf(tmx[0] - c[0], tmx[1] - c[1]), fmaxf(tmx[2] - c[2], tmx[3] - c[3]));
    if (__any(u > THR_LOG2)) {
      #pragma unroll
      for (int r = 0; r < 4; ++r) {
        float rm = redmax16(tmx[r]) + fbias;
        float mnew = fmaxf(mrow[r], rm);
        float alpha = exp2f(mrow[r] - mnew);
        mrow[r] = mnew;
        c[r] = mnew - fbias;
        lpart[r] *= alpha;
        #pragma unroll
        for (int di = 0; di < 4; ++di) acc[di][r] *= alpha;
      }
    }

    // P = exp2(s - c); lane-local l partials; P -> LDS (wave-private 16x64 block)
    #pragma unroll
    for (int r = 0; r < 4; ++r) {
      float ps = 0.f;
      #pragma unroll
      for (int ni = 0; ni < 4; ++ni) {
        float p = exp2f(s[ni][r] - c[r]);
        ps += p;
        sP[half][(wq + lg * 4 + r) * SPS + ni * 16 + l16] = (bf16_t)p;
      }
      lpart[r] += ps;
    }

    // acc += P * V  (this wave's 64 keys)
    #pragma unroll
    for (int ks = 0; ks < 2; ++ks) {
      bf16x8 pfr, vf[4];
      pfr = *reinterpret_cast<const bf16x8*>(&sP[half][(wq + l16) * SPS + ks * 32 + lg * 8]);
      #pragma unroll
      for (int di = 0; di < 4; ++di)
        vf[di] = *reinterpret_cast<const bf16x8*>(
            &sV[(di * 16 + l16) * SVS + kh0 + ks * 32 + lg * 8]);
      #pragma unroll
      for (int di = 0; di < 4; ++di)
        acc[di] = __builtin_amdgcn_mfma_f32_16x16x32_bf16(pfr, vf[di], acc[di], 0, 0, 0);
    }

    __syncthreads();                 // all waves done reading this tile
    if (pf) {
      *reinterpret_cast<bf16x8*>(kDst0) = rk0;
      *reinterpret_cast<bf16x8*>(kDst1) = rk1;
      *reinterpret_cast<bf16x8*>(vDst0) = rv0;
      *reinterpret_cast<bf16x8*>(vDst1) = rv1;
    }
    __syncthreads();                 // next tile visible
  }

  // ----- merge the two key-halves (LSE combine) -----
  float lrow[4];
  #pragma unroll
  for (int r = 0; r < 4; ++r) lrow[r] = redsum16(lpart[r]);

  if (l16 == 0) {
    #pragma unroll
    for (int r = 0; r < 4; ++r) {
      int row = wq + lg * 4 + r;
      sM[half][row] = mrow[r];
      sL[half][row] = lrow[r];
    }
  }
  __syncthreads();

  float eh[4], denom[4];
  #pragma unroll
  for (int r = 0; r < 4; ++r) {
    int row = wq + lg * 4 + r;
    float m0 = sM[0][row], m1 = sM[1][row];
    float l0 = sL[0][row], l1 = sL[1][row];
    float M = fmaxf(m0, m1);
    float e0 = exp2f(m0 - M), e1 = exp2f(m1 - M);
    denom[r] = l0 * e0 + l1 * e1;
    eh[r] = half ? e1 : e0;
  }

  if (half == 1) {    // sAcc aliases sP: all sP reads completed before last barrier
    #pragma unroll
    for (int di = 0; di < 4; ++di)
      #pragma unroll
      for (int r = 0; r < 4; ++r)
        sAcc[(wq + lg * 4 + r) * SPS + di * 16 + l16] = acc[di][r] * eh[r];
  }
  __syncthreads();

  if (half == 0) {
    #pragma unroll
    for (int di = 0; di < 4; ++di)
      #pragma unroll
      for (int r = 0; r < 4; ++r) {
        int row = wq + lg * 4 + r;
        float v = (acc[di][r] * eh[r] + sAcc[row * SPS + di * 16 + l16]) / denom[r];
        ctx[(size_t)(b * QLEN + q0 + row) * INNER + h * DKV + di * 16 + l16] = (bf16_t)v;
      }
  }
}

extern "C" void kernel_launch(void* const* d_in, const int* in_sizes, int n_in,
                              void* d_out, int out_size, void* d_ws, size_t ws_size,
                              hipStream_t stream) {
  const float* X    = (const float*)d_in[0];
  const float* Wq   = (const float*)d_in[1];
  const float* Wk   = (const float*)d_in[2];
  const float* Wv   = (const float*)d_in[3];
  const float* Wo   = (const float*)d_in[4];
  const float* relb = (const float*)d_in[5];
  float* out = (float*)d_out;

  const size_t WSZ = 262144, XSZ = 2097152;
  bf16_t* ws   = (bf16_t*)d_ws;
  bf16_t* Wq_h = ws;              bf16_t* Wq_l = Wq_h + WSZ;
  bf16_t* Wk_h = Wq_l + WSZ;      bf16_t* Wk_l = Wk_h + WSZ;
  bf16_t* Wv_h = Wk_l + WSZ;      bf16_t* Wv_l = Wv_h + WSZ;
  bf16_t* Wo_h = Wv_l + WSZ;      bf16_t* Wo_l = Wo_h + WSZ;
  bf16_t* buf0 = Wo_l + WSZ;      bf16_t* buf1 = buf0 + XSZ;
  bf16_t* Q_h  = buf1 + XSZ;      bf16_t* Q_l  = Q_h + XSZ;
  bf16_t* K_h  = Q_l + XSZ;
  bf16_t* Vt   = buf1;            // V^T [b][h*64+d][s]
  bf16_t* ctx  = buf0;            // attention output

  transpose512_split_all<<<dim3(16, 16, 4), dim3(32, 8), 0, stream>>>(
      Wq, Wk, Wv, Wo, Wq_h, Wq_l, Wk_h, Wk_l, Wv_h, Wv_l, Wo_h, Wo_l);

  gemm_qk_split<<<dim3(64, 16), 256, 0, stream>>>(X, Wq_h, Wq_l, Wk_h, Wk_l,
                                                  Q_h, Q_l, K_h);
  gemm64<1, 1><<<dim3(64, 8), 256, 0, stream>>>(nullptr, X, Wv_h, Vt, nullptr);

  attn_kernel<<<dim3(512), 512, 0, stream>>>(Q_h, Q_l, K_h, Vt, relb, ctx);

  gemm64<2, 0><<<dim3(64, 8), 256, 0, stream>>>(ctx, nullptr, Wo_h, nullptr, out);
}